// Round 7
// baseline (906.669 us; speedup 1.0000x reference)
//
#include <hip/hip_runtime.h>
#include <hip/hip_bf16.h>
#include <hip/hip_fp16.h>

// GCN forward. fp16 inter-layer tensors; gather operand fp8 e4m3; fp32
// accum everywhere.
// R3: MFMA GEMM, pre-swizzled W. R7: radix-bucketed CSR build.
// R8: 64-row GEMM tiles; fp16 residual. R10: fp8 gather operand.
// R11: BN stats 64x-replicated. R12: uint-vector gather, persisted
//     histograms, fused norms. R13: coalesced GEMM epilogues (LDS xpose).
// R15: de-fused gather (occupancy). R16: index-prefetch pipeline; merged
//     cdcs_k; gbounds folded into gout.
// R18: COLUMN-SLABBED gather. P0f8 stored slab-major: 4 slabs x 32 cols
//     (3.2 MB each < 4 MB per-XCD L2). Gather loops slabs in-kernel;
//     4 lanes/node x uint2 per slab; per-column edge order unchanged ->
//     numerics identical. Random reads now hit per-XCD L2 (~200cy)
//     instead of L3 (~600cy); nontemporal loads skip useless L1.
// R19: fix compile: __builtin_nontemporal_load rejects HIP_vector_type
//     pointers -> load via unsigned long long* and unpack (same 8B).

#define N_NODES 100000
#define N_EDGES 1600000
#define N_GRAPHS 128
#define DIM 128
#define N_LAYERS 4
#define BN_EPS 1e-5f
#define NBUCK 196          // ceil(N_NODES/512)
#define EPB 6250           // edges per block in bin/scatter passes (256 blocks)
#define SREP 64            // stats replicas (atomic-chain 1563 -> ~24)
#define SLABQ (N_NODES * 4)  // uint2 per slab (3.2 MB)

typedef __attribute__((ext_vector_type(8))) _Float16 half8;
typedef __attribute__((ext_vector_type(4))) float floatx4;
typedef __attribute__((ext_vector_type(2))) float floatx2;

// nontemporal 8B load as uint2 (builtin requires scalar-typed pointer)
__device__ inline uint2 ntload_u2(const uint2* p) {
  unsigned long long v =
      __builtin_nontemporal_load((const unsigned long long*)p);
  uint2 r;
  r.x = (unsigned)v;
  r.y = (unsigned)(v >> 32);
  return r;
}

// ---------------- pass A: bucket counts + per-block histograms ----------------
__global__ __launch_bounds__(256) void binA_k(const int* __restrict__ src,
                                              const int* __restrict__ dst,
                                              int* __restrict__ cnt_d,
                                              int* __restrict__ cnt_s,
                                              int* __restrict__ bh_d,
                                              int* __restrict__ bh_s) {
  __shared__ int hd[NBUCK], hs[NBUCK];
  int t = threadIdx.x;
  for (int i = t; i < NBUCK; i += 256) { hd[i] = 0; hs[i] = 0; }
  __syncthreads();
  int e0 = blockIdx.x * EPB;
  for (int e = e0 + t; e < e0 + EPB; e += 256) {
    atomicAdd(&hd[dst[e] >> 9], 1);
    atomicAdd(&hs[src[e] >> 9], 1);
  }
  __syncthreads();
  for (int i = t; i < NBUCK; i += 256) {
    int v = hd[i], v2 = hs[i];
    bh_d[blockIdx.x * NBUCK + i] = v;
    bh_s[blockIdx.x * NBUCK + i] = v2;
    if (v) atomicAdd(&cnt_d[i], v);
    if (v2) atomicAdd(&cnt_s[i], v2);
  }
}

// ---------------- scan of bucket counts -> bases + cursors ----------------
__global__ __launch_bounds__(256) void scan196_k(
    const int* __restrict__ cnt_d, const int* __restrict__ cnt_s,
    int* __restrict__ base_d, int* __restrict__ cur_d,
    int* __restrict__ base_s, int* __restrict__ cur_s,
    int* __restrict__ row_start) {
  __shared__ int sd[256], ss[256];
  int t = threadIdx.x;
  int vd = (t < NBUCK) ? cnt_d[t] : 0;
  int vs = (t < NBUCK) ? cnt_s[t] : 0;
  sd[t] = vd;
  ss[t] = vs;
  __syncthreads();
  for (int off = 1; off < 256; off <<= 1) {
    int ad = (t >= off) ? sd[t - off] : 0;
    int as = (t >= off) ? ss[t - off] : 0;
    __syncthreads();
    sd[t] += ad;
    ss[t] += as;
    __syncthreads();
  }
  if (t < NBUCK) {
    base_d[t] = sd[t] - vd;
    cur_d[t] = sd[t] - vd;
    base_s[t] = ss[t] - vs;
    cur_s[t] = ss[t] - vs;
  }
  if (t == 0) {
    base_d[NBUCK] = N_EDGES;
    base_s[NBUCK] = N_EDGES;
    row_start[N_NODES] = N_EDGES;
  }
}

// ---------------- pass B: scatter edges into bucket regions ----------------
__global__ __launch_bounds__(256) void scat_k(
    const int* __restrict__ src, const int* __restrict__ dst,
    int* __restrict__ cur_d, int* __restrict__ cur_s,
    const int* __restrict__ bh_d, const int* __restrict__ bh_s,
    int* __restrict__ packed, unsigned short* __restrict__ locs) {
  __shared__ int hd[NBUCK], hs[NBUCK];
  int t = threadIdx.x;
  for (int i = t; i < NBUCK; i += 256) {
    hd[i] = bh_d[blockIdx.x * NBUCK + i];
    hs[i] = bh_s[blockIdx.x * NBUCK + i];
  }
  __syncthreads();
  if (t < NBUCK) {  // claim chunks; hd/hs become running cursors
    hd[t] = atomicAdd(&cur_d[t], hd[t]);
    hs[t] = atomicAdd(&cur_s[t], hs[t]);
  }
  __syncthreads();
  int e0 = blockIdx.x * EPB;
  for (int e = e0 + t; e < e0 + EPB; e += 256) {
    int s = src[e], d = dst[e];
    int slot = atomicAdd(&hd[d >> 9], 1);
    packed[slot] = ((d & 511) << 17) | s;
    int slot2 = atomicAdd(&hs[s >> 9], 1);
    locs[slot2] = (unsigned short)(s & 511);
  }
}

// ---------------- pass C (merged): dst CSR fill + norms ----------------
__global__ __launch_bounds__(256) void cdcs_k(
    const int* __restrict__ base_d, const int* __restrict__ packed,
    int* __restrict__ row_start, int* __restrict__ csr_src,
    float* __restrict__ norm_dst, const int* __restrict__ base_s,
    const unsigned short* __restrict__ locs, float* __restrict__ norm_src) {
  __shared__ int sdeg[512], sinc[512], scur[512];
  int t = threadIdx.x;
  if (blockIdx.x >= NBUCK) {  // ---- src-degree histogram -> norm_src ----
    int b = blockIdx.x - NBUCK;
    int nbase = b << 9;
    int e0 = base_s[b], e1 = base_s[b + 1];
    sdeg[t] = 0;
    sdeg[t + 256] = 0;
    __syncthreads();
    for (int e = e0 + t; e < e1; e += 256) atomicAdd(&sdeg[locs[e]], 1);
    __syncthreads();
#pragma unroll
    for (int half = 0; half < 2; ++half) {
      int j = t + half * 256;
      int node = nbase + j;
      if (node < N_NODES) {
        int d = sdeg[j];
        norm_src[node] = rsqrtf((float)(d > 1 ? d : 1));
      }
    }
    return;
  }
  // ---- dst side ----
  int b = blockIdx.x;
  int nbase = b << 9;
  int e0 = base_d[b], e1 = base_d[b + 1];
  sdeg[t] = 0;
  sdeg[t + 256] = 0;
  __syncthreads();
  for (int e = e0 + t; e < e1; e += 256) atomicAdd(&sdeg[packed[e] >> 17], 1);
  __syncthreads();
  sinc[t] = sdeg[t];
  sinc[t + 256] = sdeg[t + 256];
  __syncthreads();
  for (int off = 1; off < 512; off <<= 1) {
    int a0 = (t >= off) ? sinc[t - off] : 0;
    int i1 = t + 256;
    int a1 = (i1 >= off) ? sinc[i1 - off] : 0;
    __syncthreads();
    sinc[t] += a0;
    sinc[i1] += a1;
    __syncthreads();
  }
#pragma unroll
  for (int half = 0; half < 2; ++half) {
    int j = t + half * 256;
    int lofs = e0 + sinc[j] - sdeg[j];
    scur[j] = lofs;
    int node = nbase + j;
    if (node < N_NODES) {
      row_start[node] = lofs;
      int d = sdeg[j];
      norm_dst[node] = rsqrtf((float)(d > 1 ? d : 1));
    }
  }
  __syncthreads();
  for (int e = e0 + t; e < e1; e += 256) {
    int p = packed[e];
    int slot = atomicAdd(&scur[p >> 17], 1);
    csr_src[slot] = p & 0x1FFFF;
  }
}

// ---------------- W pre-swizzle (all 5 matrices, one launch) ----------------
__global__ __launch_bounds__(256) void wswz_k(const float* __restrict__ W_embed,
                                              const float* __restrict__ W_layers,
                                              __half* __restrict__ Bsw) {
  int m = blockIdx.x >> 3, ct = blockIdx.x & 7;  // m: 0=embed, 1..4=layers
  const float* Wm =
      (m == 0) ? W_embed : (W_layers + (size_t)(m - 1) * 16384);
  int ks = threadIdx.x >> 6, lane = threadIdx.x & 63;
  int n = ct * 16 + (lane & 15);
  int k0 = ks * 32 + (lane >> 4) * 8;
  __half* o = Bsw + ((((size_t)m * 8 + ct) * 4 + ks) * 64 + lane) * 8;
#pragma unroll
  for (int j = 0; j < 8; ++j) o[j] = __float2half(Wm[(k0 + j) * 128 + n]);
}

// ---------------- MFMA core: wave w computes 16 rows x 128 cols ----------
// C layout per 16x16 tile: row = quad*4 + reg, col = ct*16 + lrow.
__device__ inline void mfma_core16(const __half* sA,
                                   const __half* __restrict__ Bsw,
                                   floatx4 (&acc)[8], int w, int lane,
                                   int quad, int lrow) {
#pragma unroll
  for (int ct = 0; ct < 8; ++ct) acc[ct] = (floatx4)(0.f);
#pragma unroll
  for (int ks = 0; ks < 4; ++ks) {
    int m = w * 16 + lrow;
    half8 afrag = *(const half8*)(&sA[m * 136 + ks * 32 + quad * 8]);
#pragma unroll
    for (int ct = 0; ct < 8; ++ct) {
      half8 bfrag = *(const half8*)(&Bsw[(((size_t)ct * 4 + ks) * 64 + lane) * 8]);
      acc[ct] = __builtin_amdgcn_mfma_f32_16x16x32_f16(afrag, bfrag, acc[ct],
                                                       0, 0, 0);
    }
  }
}

// ---------------- fp8 accumulate helper (8 cols / lane) ----------------
__device__ inline void accf8x8(float (&a)[8], uint2 v) {
  floatx2 f;
  f = __builtin_amdgcn_cvt_pk_f32_fp8(v.x, false); a[0] += f.x; a[1] += f.y;
  f = __builtin_amdgcn_cvt_pk_f32_fp8(v.x, true);  a[2] += f.x; a[3] += f.y;
  f = __builtin_amdgcn_cvt_pk_f32_fp8(v.y, false); a[4] += f.x; a[5] += f.y;
  f = __builtin_amdgcn_cvt_pk_f32_fp8(v.y, true);  a[6] += f.x; a[7] += f.y;
}

// ---------------- embed GEMM: A16 = fp16(h @ W + b); S8 = fp8(.*ns) ------
// Epilogue: fp32 C staged to LDS in two 32-row rounds -> coalesced stores.
// S8 written SLAB-MAJOR: slab = col>>5, word (row*32 + (col&31))/4.
__global__ __launch_bounds__(256) void mfma_gemm_f32in(
    const float* __restrict__ X32, const __half* __restrict__ Bsw,
    const float* __restrict__ bias, __half* __restrict__ A16,
    unsigned char* __restrict__ S8, const float* __restrict__ norm_src) {
  __shared__ __half sA[64 * 136];  // 17.4 KB; reused as fp32 C half-tile
  const int tid = threadIdx.x;
  const int w = tid >> 6, lane = tid & 63;
  const int quad = lane >> 4, lrow = lane & 15;
  const int row_base = blockIdx.x * 64;

  // stage fp32 tile -> fp16 LDS (2048 float4 reads)
#pragma unroll
  for (int i = 0; i < 8; ++i) {
    int g = i * 256 + tid;
    int r = g >> 5, q = g & 31;
    int row = row_base + r;
    float4 v = make_float4(0.f, 0.f, 0.f, 0.f);
    if (row < N_NODES) v = ((const float4*)X32)[(size_t)row * 32 + q];
    union { __half2 h[2]; float f[2]; } u;
    u.h[0] = __floats2half2_rn(v.x, v.y);
    u.h[1] = __floats2half2_rn(v.z, v.w);
    *(float2*)(&sA[r * 136 + q * 4]) = *(float2*)u.f;
  }
  __syncthreads();

  floatx4 acc[8];
  mfma_core16(sA, Bsw, acc, w, lane, quad, lrow);

  float bcol[8];
#pragma unroll
  for (int ct = 0; ct < 8; ++ct) bcol[ct] = bias[ct * 16 + lrow];

  float* sC = (float*)sA;  // [32][132] fp32 (16896 B <= 17408 B)
#pragma unroll
  for (int h = 0; h < 2; ++h) {
    __syncthreads();  // h=0: all mfma LDS reads done; h=1: readback done
    if ((w >> 1) == h) {
      int hw = w & 1;
#pragma unroll
      for (int ct = 0; ct < 8; ++ct)
#pragma unroll
        for (int reg = 0; reg < 4; ++reg)
          sC[(hw * 16 + quad * 4 + reg) * 132 + ct * 16 + lrow] =
              acc[ct][reg] + bcol[ct];
    }
    __syncthreads();
#pragma unroll
    for (int k = 0; k < 4; ++k) {
      int c = k * 256 + tid;       // chunk 0..1023 (16B of fp32 each)
      int hr = c >> 5;             // 0..31
      int col = (c & 31) * 4;
      int row = row_base + h * 32 + hr;
      if (row < N_NODES) {
        float4 y = *(const float4*)&sC[hr * 132 + col];
        union { __half2 hh[2]; float2 f; } u;
        u.hh[0] = __floats2half2_rn(y.x, y.y);
        u.hh[1] = __floats2half2_rn(y.z, y.w);
        *(float2*)(A16 + (size_t)row * 128 + col) = u.f;
        float ns = norm_src[row];
        unsigned pb = 0;
        pb = __builtin_amdgcn_cvt_pk_fp8_f32(y.x * ns, y.y * ns, pb, false);
        pb = __builtin_amdgcn_cvt_pk_fp8_f32(y.z * ns, y.w * ns, pb, true);
        // slab-major: slab = col>>5, 4B word index within slab
        ((unsigned*)S8)[(size_t)(col >> 5) * (N_NODES * 8) + row * 8 +
                        ((col & 31) >> 2)] = pb;
      }
    }
  }
}

// ---------------- slabbed gather: 4 lanes/node/slab, L2-resident slabs ----
// Slab = 32 cols (3.2 MB < 4 MB per-XCD L2). Lane l4 owns cols
// slab*32 + l4*8 (uint2). Edge order per column unchanged -> numerics
// identical. Nontemporal loads: random operand, L1 useless.
__global__ __launch_bounds__(256, 8) void gather4_k(
    const uint2* __restrict__ Hs, const int* __restrict__ row_start,
    const int* __restrict__ csr_src, const float* __restrict__ norm_dst,
    __half* __restrict__ out) {
  int node = (blockIdx.x * 256 + threadIdx.x) >> 2;
  int l4 = threadIdx.x & 3;
  if (node >= N_NODES) return;
  int s0 = row_start[node], s1 = row_start[node + 1];
  int deg = s1 - s0;
  int nfull = deg >> 3;
  float nd = norm_dst[node];
#pragma unroll 1
  for (int slab = 0; slab < 4; ++slab) {
    const uint2* Hsl = Hs + (size_t)slab * SLABQ;
    float a[8];
#pragma unroll
    for (int i = 0; i < 8; ++i) a[i] = 0.f;
    int e = s0;
    if (nfull) {
      int idxA = csr_src[e + l4];
      int idxB = csr_src[e + 4 + l4];
      for (int k = 0; k < nfull; ++k) {
        uint2 v0 = ntload_u2(&Hsl[(size_t)__shfl(idxA, 0, 4) * 4 + l4]);
        uint2 v1 = ntload_u2(&Hsl[(size_t)__shfl(idxA, 1, 4) * 4 + l4]);
        uint2 v2 = ntload_u2(&Hsl[(size_t)__shfl(idxA, 2, 4) * 4 + l4]);
        uint2 v3 = ntload_u2(&Hsl[(size_t)__shfl(idxA, 3, 4) * 4 + l4]);
        uint2 v4 = ntload_u2(&Hsl[(size_t)__shfl(idxB, 0, 4) * 4 + l4]);
        uint2 v5 = ntload_u2(&Hsl[(size_t)__shfl(idxB, 1, 4) * 4 + l4]);
        uint2 v6 = ntload_u2(&Hsl[(size_t)__shfl(idxB, 2, 4) * 4 + l4]);
        uint2 v7 = ntload_u2(&Hsl[(size_t)__shfl(idxB, 3, 4) * 4 + l4]);
        // prefetch next chunk's indices (clamped; unused on last iter)
        int pa = e + 8 + l4, pb = e + 12 + l4;
        int idxA_n = csr_src[pa < N_EDGES ? pa : (N_EDGES - 1)];
        int idxB_n = csr_src[pb < N_EDGES ? pb : (N_EDGES - 1)];
        accf8x8(a, v0); accf8x8(a, v1); accf8x8(a, v2); accf8x8(a, v3);
        accf8x8(a, v4); accf8x8(a, v5); accf8x8(a, v6); accf8x8(a, v7);
        idxA = idxA_n;
        idxB = idxB_n;
        e += 8;
      }
    }
    int cnt = s1 - e;
    if (cnt) {
      int iA = (l4 < cnt) ? csr_src[e + l4] : 0;
      int iB = (4 + l4 < cnt) ? csr_src[e + 4 + l4] : 0;
      int jm = cnt < 4 ? cnt : 4;
      for (int j = 0; j < jm; ++j)
        accf8x8(a, ntload_u2(&Hsl[(size_t)__shfl(iA, j, 4) * 4 + l4]));
      for (int j = 4; j < cnt; ++j)
        accf8x8(a, ntload_u2(&Hsl[(size_t)__shfl(iB, j - 4, 4) * 4 + l4]));
    }
    union { __half2 hh[4]; float4 f; } u;
#pragma unroll
    for (int q = 0; q < 4; ++q)
      u.hh[q] = __floats2half2_rn(a[2 * q] * nd, a[2 * q + 1] * nd);
    *(float4*)(out + (size_t)node * 128 + slab * 32 + l4 * 8) = u.f;
  }
}

// ---------------- layer GEMM: hl16 = fp16(agg16 @ W + b) + BN stats -------
__global__ __launch_bounds__(256) void mfma_gemm_f16(
    const __half* __restrict__ X16, const __half* __restrict__ Bsw,
    const float* __restrict__ bias, __half* __restrict__ hl16,
    float* __restrict__ stats) {
  __shared__ __half sA[64 * 136];  // A-tile fp16; reused as fp32 C half-tile
  __shared__ float sred[1024];     // cross-wave stats scratch
  const int tid = threadIdx.x;
  const int w = tid >> 6, lane = tid & 63;
  const int quad = lane >> 4, lrow = lane & 15;
  const int row_base = blockIdx.x * 64;

  // stage fp16 tile (1024 float4 reads)
#pragma unroll
  for (int i = 0; i < 4; ++i) {
    int g = i * 256 + tid;
    int r = g >> 4, p = g & 15;
    int row = row_base + r;
    float4 v = make_float4(0.f, 0.f, 0.f, 0.f);
    if (row < N_NODES) v = ((const float4*)X16)[(size_t)row * 16 + p];
    *(float4*)(&sA[r * 136 + p * 8]) = v;
  }
  __syncthreads();

  floatx4 acc[8];
  mfma_core16(sA, Bsw, acc, w, lane, quad, lrow);

  // ---- BN stats from fp32 registers ----
  float bcol[8], psum[8], pqsum[8];
#pragma unroll
  for (int ct = 0; ct < 8; ++ct) {
    bcol[ct] = bias[ct * 16 + lrow];
    psum[ct] = 0.f;
    pqsum[ct] = 0.f;
#pragma unroll
    for (int reg = 0; reg < 4; ++reg) {
      int row = row_base + w * 16 + quad * 4 + reg;
      if (row < N_NODES) {
        float y = acc[ct][reg] + bcol[ct];
        psum[ct] += y;
        pqsum[ct] += y * y;
      }
    }
  }
#pragma unroll
  for (int ct = 0; ct < 8; ++ct) {
    psum[ct] += __shfl_xor(psum[ct], 16, 64);
    psum[ct] += __shfl_xor(psum[ct], 32, 64);
    pqsum[ct] += __shfl_xor(pqsum[ct], 16, 64);
    pqsum[ct] += __shfl_xor(pqsum[ct], 32, 64);
  }
  if (quad == 0) {
#pragma unroll
    for (int ct = 0; ct < 8; ++ct) {
      sred[w * 128 + ct * 16 + lrow] = psum[ct];
      sred[512 + w * 128 + ct * 16 + lrow] = pqsum[ct];
    }
  }
  __syncthreads();
  if (tid < 128) {
    float s = sred[tid] + sred[128 + tid] + sred[256 + tid] + sred[384 + tid];
    float q = sred[512 + tid] + sred[640 + tid] + sred[768 + tid] +
              sred[896 + tid];
    float* st = stats + (size_t)(blockIdx.x & (SREP - 1)) * 256;
    atomicAdd(&st[tid], s);
    atomicAdd(&st[128 + tid], q);
  }

  // ---- coalesced hl16 store via fp32 LDS transpose ----
  float* sC = (float*)sA;  // [32][132] fp32
#pragma unroll
  for (int h = 0; h < 2; ++h) {
    __syncthreads();  // h=0: mfma reads + stats barrier done; h=1: readback done
    if ((w >> 1) == h) {
      int hw = w & 1;
#pragma unroll
      for (int ct = 0; ct < 8; ++ct)
#pragma unroll
        for (int reg = 0; reg < 4; ++reg)
          sC[(hw * 16 + quad * 4 + reg) * 132 + ct * 16 + lrow] =
              acc[ct][reg] + bcol[ct];
    }
    __syncthreads();
#pragma unroll
    for (int k = 0; k < 4; ++k) {
      int c = k * 256 + tid;
      int hr = c >> 5;
      int col = (c & 31) * 4;
      int row = row_base + h * 32 + hr;
      if (row < N_NODES) {
        float4 y = *(const float4*)&sC[hr * 132 + col];
        union { __half2 hh[2]; float2 f; } u;
        u.hh[0] = __floats2half2_rn(y.x, y.y);
        u.hh[1] = __floats2half2_rn(y.z, y.w);
        *(float2*)(hl16 + (size_t)row * 128 + col) = u.f;
      }
    }
  }
}

// ---------------- BN finalize: collapse SREP replicas -> sc_sh ----------
__global__ __launch_bounds__(128) void bn_fin_k(const float* __restrict__ stats,
                                                const float* __restrict__ gamma,
                                                const float* __restrict__ beta,
                                                float* __restrict__ sc_sh) {
  int c = threadIdx.x;
  float s = 0.f, q = 0.f;
  for (int r = 0; r < SREP; ++r) {
    s += stats[r * 256 + c];
    q += stats[r * 256 + 128 + c];
  }
  const float invn = 1.0f / (float)N_NODES;
  float mean = s * invn;
  float var = q * invn - mean * mean;
  var = fmaxf(var, 0.f);
  float sc = gamma[c] * rsqrtf(var + BN_EPS);
  sc_sh[c] = sc;
  sc_sh[128 + c] = beta[c] - mean * sc;
}

// ---------------- BN apply + ReLU + residual ----------------
// S8 written SLAB-MAJOR: slab = c8>>2, uint2 slot node*4 + (c8&3).
__global__ __launch_bounds__(256) void bnrelu_k(
    const __half* __restrict__ hl16, __half* __restrict__ A16,
    unsigned char* __restrict__ S8, const float* __restrict__ sc_sh,
    const float* __restrict__ norm_src, int write_scaled) {
  int idx = blockIdx.x * 256 + threadIdx.x;  // < N_NODES*16
  int node = idx >> 4;
  int c8 = idx & 15;
  float4 hv4 = *(const float4*)(hl16 + (size_t)idx * 8);
  float4 av4 = *(const float4*)(A16 + (size_t)idx * 8);
  const __half2* hp = (const __half2*)&hv4;
  const __half2* ap = (const __half2*)&av4;
  const float4* sv = (const float4*)sc_sh;
  float4 s0 = sv[c8 * 2], s1 = sv[c8 * 2 + 1];
  float4 b0 = sv[32 + c8 * 2], b1 = sv[32 + c8 * 2 + 1];
  float n = write_scaled ? norm_src[node] : 0.f;
  float2 f0 = __half22float2(hp[0]), f1 = __half22float2(hp[1]);
  float2 f2 = __half22float2(hp[2]), f3 = __half22float2(hp[3]);
  float2 a0 = __half22float2(ap[0]), a1 = __half22float2(ap[1]);
  float2 a2 = __half22float2(ap[2]), a3 = __half22float2(ap[3]);
  float v[8];
  v[0] = fmaxf(f0.x * s0.x + b0.x, 0.f) + a0.x;
  v[1] = fmaxf(f0.y * s0.y + b0.y, 0.f) + a0.y;
  v[2] = fmaxf(f1.x * s0.z + b0.z, 0.f) + a1.x;
  v[3] = fmaxf(f1.y * s0.w + b0.w, 0.f) + a1.y;
  v[4] = fmaxf(f2.x * s1.x + b1.x, 0.f) + a2.x;
  v[5] = fmaxf(f2.y * s1.y + b1.y, 0.f) + a2.y;
  v[6] = fmaxf(f3.x * s1.z + b1.z, 0.f) + a3.x;
  v[7] = fmaxf(f3.y * s1.w + b1.w, 0.f) + a3.y;
  union { __half2 h[4]; float4 f; } ua;
#pragma unroll
  for (int q = 0; q < 4; ++q)
    ua.h[q] = __floats2half2_rn(v[2 * q], v[2 * q + 1]);
  *(float4*)(A16 + (size_t)idx * 8) = ua.f;
  if (write_scaled) {
    unsigned lo = 0, hi = 0;
    lo = __builtin_amdgcn_cvt_pk_fp8_f32(v[0] * n, v[1] * n, lo, false);
    lo = __builtin_amdgcn_cvt_pk_fp8_f32(v[2] * n, v[3] * n, lo, true);
    hi = __builtin_amdgcn_cvt_pk_fp8_f32(v[4] * n, v[5] * n, hi, false);
    hi = __builtin_amdgcn_cvt_pk_fp8_f32(v[6] * n, v[7] * n, hi, true);
    ((uint2*)S8)[(size_t)(c8 >> 2) * SLABQ + node * 4 + (c8 & 3)] =
        make_uint2(lo, hi);
  }
}

// ---------------- readout ----------------
__global__ __launch_bounds__(128) void gsum_k(const __half* __restrict__ A16,
                                              const int* __restrict__ gid,
                                              float* gsum) {
  int c = threadIdx.x;
  int n0 = blockIdx.x * 128;
  int n1 = n0 + 128;
  if (n1 > N_NODES) n1 = N_NODES;
  int cur = gid[n0];
  float local = 0.f;
  for (int n = n0; n < n1; ++n) {
    int g = gid[n];  // sorted: few changes per block
    if (g != cur) {
      atomicAdd(&gsum[cur * 128 + c], local);
      local = 0.f;
      cur = g;
    }
    local += __half2float(A16[(size_t)n * 128 + c]);
  }
  atomicAdd(&gsum[cur * 128 + c], local);
}

// gout with inline graph-bounds binary search.
__global__ __launch_bounds__(128) void gout_k(const float* __restrict__ gsum,
                                              const int* __restrict__ gid,
                                              float* __restrict__ out) {
  __shared__ int bnd[2];
  int g = blockIdx.x, c = threadIdx.x;
  if (c < 2) {
    int target = g + c;
    int lo = 0, hi = N_NODES;
    while (lo < hi) {
      int mid = (lo + hi) >> 1;
      if (gid[mid] < target) lo = mid + 1; else hi = mid;
    }
    bnd[c] = lo;
  }
  __syncthreads();
  float cnt = (float)(bnd[1] - bnd[0]);
  if (cnt < 1.f) cnt = 1.f;
  out[g * 128 + c] = gsum[g * 128 + c] / cnt;
}

// ---------------- launch ----------------
extern "C" void kernel_launch(void* const* d_in, const int* in_sizes, int n_in,
                              void* d_out, int out_size, void* d_ws,
                              size_t ws_size, hipStream_t stream) {
  const float* h = (const float*)d_in[0];
  const int* src = (const int*)d_in[1];
  const int* dst = (const int*)d_in[2];
  const int* gid = (const int*)d_in[3];
  const float* W_embed = (const float*)d_in[4];
  const float* b_embed = (const float*)d_in[5];
  const float* W_layers = (const float*)d_in[6];
  const float* b_layers = (const float*)d_in[7];
  const float* gamma = (const float*)d_in[8];
  const float* beta = (const float*)d_in[9];
  float* out = (float*)d_out;
  (void)in_sizes; (void)n_in; (void)out_size; (void)ws_size;

  char* ws = (char*)d_ws;
  size_t o = 0;
  auto alloc = [&](size_t bytes) -> char* {
    char* p = ws + o;
    o = (o + bytes + 255) & ~(size_t)255;
    return p;
  };
  int* cnt_d = (int*)alloc(NBUCK * 4);  // zeroed (one memset w/ cnt_s)
  int* cnt_s = (int*)alloc(NBUCK * 4);
  int* base_d = (int*)alloc((NBUCK + 1) * 4);
  int* cur_d = (int*)alloc(NBUCK * 4);
  int* base_s = (int*)alloc((NBUCK + 1) * 4);
  int* cur_s = (int*)alloc(NBUCK * 4);
  int* bh_d = (int*)alloc((size_t)256 * NBUCK * 4);
  int* bh_s = (int*)alloc((size_t)256 * NBUCK * 4);
  float* norm_src = (float*)alloc(N_NODES * 4);
  float* norm_dst = (float*)alloc(N_NODES * 4);
  int* row_start = (int*)alloc((N_NODES + 1) * 4);
  int* csr_src = (int*)alloc((size_t)N_EDGES * 4);
  int* packed = (int*)alloc((size_t)N_EDGES * 4);
  unsigned short* locs = (unsigned short*)alloc((size_t)N_EDGES * 2);
  float* stats4 = (float*)alloc((size_t)N_LAYERS * SREP * 256 * 4);
  float* gsum = (float*)alloc(N_GRAPHS * 128 * 4);  // adjacent to stats4
  float* sc_sh = (float*)alloc(256 * 4);
  __half* Bsw = (__half*)alloc(5 * 16384 * 2);
  __half* A16 = (__half*)alloc((size_t)N_NODES * 128 * 2);  // residual (fp16)
  unsigned char* P0f8 = (unsigned char*)alloc((size_t)N_NODES * 128);  // fp8, slab-major
  __half* P1h = (__half*)alloc((size_t)N_NODES * 128 * 2);  // agg (fp16)
  __half* H16 = (__half*)alloc((size_t)N_NODES * 128 * 2);  // hl (fp16)

  // zero bucket counters; zero all per-layer stats replicas + gsum
  hipMemsetAsync(cnt_d, 0, 2048, stream);
  hipMemsetAsync(stats4, 0, (size_t)N_LAYERS * SREP * 256 * 4 + 65536, stream);

  // ---- radix CSR build ----
  binA_k<<<256, 256, 0, stream>>>(src, dst, cnt_d, cnt_s, bh_d, bh_s);
  scan196_k<<<1, 256, 0, stream>>>(cnt_d, cnt_s, base_d, cur_d, base_s, cur_s,
                                   row_start);
  scat_k<<<256, 256, 0, stream>>>(src, dst, cur_d, cur_s, bh_d, bh_s, packed,
                                  locs);
  cdcs_k<<<2 * NBUCK, 256, 0, stream>>>(base_d, packed, row_start, csr_src,
                                        norm_dst, base_s, locs, norm_src);

  wswz_k<<<40, 256, 0, stream>>>(W_embed, W_layers, Bsw);

  // embed: A16 = fp16(h @ W_embed + b) ; P0f8 = fp8(. * norm_src), slab-major
  mfma_gemm_f32in<<<(N_NODES + 63) / 64, 256, 0, stream>>>(
      h, Bsw, b_embed, A16, P0f8, norm_src);

  for (int l = 0; l < N_LAYERS; ++l) {
    float* stats = stats4 + (size_t)l * SREP * 256;
    gather4_k<<<(N_NODES * 4 + 255) / 256, 256, 0, stream>>>(
        (const uint2*)P0f8, row_start, csr_src, norm_dst, P1h);
    mfma_gemm_f16<<<(N_NODES + 63) / 64, 256, 0, stream>>>(
        P1h, Bsw + (size_t)(1 + l) * 16384, b_layers + l * DIM, H16, stats);
    bn_fin_k<<<1, 128, 0, stream>>>(stats, gamma + l * DIM, beta + l * DIM,
                                    sc_sh);
    bnrelu_k<<<(N_NODES * 16 + 255) / 256, 256, 0, stream>>>(
        H16, A16, P0f8, sc_sh, norm_src, (l < N_LAYERS - 1) ? 1 : 0);
  }

  gsum_k<<<(N_NODES + 127) / 128, 128, 0, stream>>>(A16, gid, gsum);
  gout_k<<<N_GRAPHS, 128, 0, stream>>>(gsum, gid, out);
}

// Round 8
// 644.397 us; speedup vs baseline: 1.4070x; 1.4070x over previous
//
#include <hip/hip_runtime.h>
#include <hip/hip_bf16.h>
#include <hip/hip_fp16.h>

// GCN forward. fp16 inter-layer tensors; gather operand fp8 e4m3; fp32
// accum everywhere.
// R3: MFMA GEMM, pre-swizzled W. R7: radix-bucketed CSR build.
// R8: 64-row GEMM tiles; fp16 residual. R10: fp8 gather operand.
// R11: BN stats 64x-replicated. R12: uint-vector gather, persisted
//     histograms, fused norms. R13: coalesced GEMM epilogues (LDS xpose).
// R15: de-fused gather (occupancy). R16: index-prefetch pipeline; merged
//     cdcs_k; gbounds folded into gout.
// R18: COLUMN-SLABBED gather: P0f8 slab-major, 4 slabs x 32 cols (3.2 MB
//     < 4 MB per-XCD L2); 4 lanes/node/slab; edge order per column
//     unchanged -> numerics identical.
// R20: REMOVE nontemporal loads (R19's nt flag defeated L2/L3 entirely:
//     FETCH 78->257 MB, gather 32->130 us). Plain loads let each slab go
//     L2-resident per XCD. Everything else identical to R19.

#define N_NODES 100000
#define N_EDGES 1600000
#define N_GRAPHS 128
#define DIM 128
#define N_LAYERS 4
#define BN_EPS 1e-5f
#define NBUCK 196          // ceil(N_NODES/512)
#define EPB 6250           // edges per block in bin/scatter passes (256 blocks)
#define SREP 64            // stats replicas (atomic-chain 1563 -> ~24)
#define SLABQ (N_NODES * 4)  // uint2 per slab (3.2 MB)

typedef __attribute__((ext_vector_type(8))) _Float16 half8;
typedef __attribute__((ext_vector_type(4))) float floatx4;
typedef __attribute__((ext_vector_type(2))) float floatx2;

// ---------------- pass A: bucket counts + per-block histograms ----------------
__global__ __launch_bounds__(256) void binA_k(const int* __restrict__ src,
                                              const int* __restrict__ dst,
                                              int* __restrict__ cnt_d,
                                              int* __restrict__ cnt_s,
                                              int* __restrict__ bh_d,
                                              int* __restrict__ bh_s) {
  __shared__ int hd[NBUCK], hs[NBUCK];
  int t = threadIdx.x;
  for (int i = t; i < NBUCK; i += 256) { hd[i] = 0; hs[i] = 0; }
  __syncthreads();
  int e0 = blockIdx.x * EPB;
  for (int e = e0 + t; e < e0 + EPB; e += 256) {
    atomicAdd(&hd[dst[e] >> 9], 1);
    atomicAdd(&hs[src[e] >> 9], 1);
  }
  __syncthreads();
  for (int i = t; i < NBUCK; i += 256) {
    int v = hd[i], v2 = hs[i];
    bh_d[blockIdx.x * NBUCK + i] = v;
    bh_s[blockIdx.x * NBUCK + i] = v2;
    if (v) atomicAdd(&cnt_d[i], v);
    if (v2) atomicAdd(&cnt_s[i], v2);
  }
}

// ---------------- scan of bucket counts -> bases + cursors ----------------
__global__ __launch_bounds__(256) void scan196_k(
    const int* __restrict__ cnt_d, const int* __restrict__ cnt_s,
    int* __restrict__ base_d, int* __restrict__ cur_d,
    int* __restrict__ base_s, int* __restrict__ cur_s,
    int* __restrict__ row_start) {
  __shared__ int sd[256], ss[256];
  int t = threadIdx.x;
  int vd = (t < NBUCK) ? cnt_d[t] : 0;
  int vs = (t < NBUCK) ? cnt_s[t] : 0;
  sd[t] = vd;
  ss[t] = vs;
  __syncthreads();
  for (int off = 1; off < 256; off <<= 1) {
    int ad = (t >= off) ? sd[t - off] : 0;
    int as = (t >= off) ? ss[t - off] : 0;
    __syncthreads();
    sd[t] += ad;
    ss[t] += as;
    __syncthreads();
  }
  if (t < NBUCK) {
    base_d[t] = sd[t] - vd;
    cur_d[t] = sd[t] - vd;
    base_s[t] = ss[t] - vs;
    cur_s[t] = ss[t] - vs;
  }
  if (t == 0) {
    base_d[NBUCK] = N_EDGES;
    base_s[NBUCK] = N_EDGES;
    row_start[N_NODES] = N_EDGES;
  }
}

// ---------------- pass B: scatter edges into bucket regions ----------------
__global__ __launch_bounds__(256) void scat_k(
    const int* __restrict__ src, const int* __restrict__ dst,
    int* __restrict__ cur_d, int* __restrict__ cur_s,
    const int* __restrict__ bh_d, const int* __restrict__ bh_s,
    int* __restrict__ packed, unsigned short* __restrict__ locs) {
  __shared__ int hd[NBUCK], hs[NBUCK];
  int t = threadIdx.x;
  for (int i = t; i < NBUCK; i += 256) {
    hd[i] = bh_d[blockIdx.x * NBUCK + i];
    hs[i] = bh_s[blockIdx.x * NBUCK + i];
  }
  __syncthreads();
  if (t < NBUCK) {  // claim chunks; hd/hs become running cursors
    hd[t] = atomicAdd(&cur_d[t], hd[t]);
    hs[t] = atomicAdd(&cur_s[t], hs[t]);
  }
  __syncthreads();
  int e0 = blockIdx.x * EPB;
  for (int e = e0 + t; e < e0 + EPB; e += 256) {
    int s = src[e], d = dst[e];
    int slot = atomicAdd(&hd[d >> 9], 1);
    packed[slot] = ((d & 511) << 17) | s;
    int slot2 = atomicAdd(&hs[s >> 9], 1);
    locs[slot2] = (unsigned short)(s & 511);
  }
}

// ---------------- pass C (merged): dst CSR fill + norms ----------------
__global__ __launch_bounds__(256) void cdcs_k(
    const int* __restrict__ base_d, const int* __restrict__ packed,
    int* __restrict__ row_start, int* __restrict__ csr_src,
    float* __restrict__ norm_dst, const int* __restrict__ base_s,
    const unsigned short* __restrict__ locs, float* __restrict__ norm_src) {
  __shared__ int sdeg[512], sinc[512], scur[512];
  int t = threadIdx.x;
  if (blockIdx.x >= NBUCK) {  // ---- src-degree histogram -> norm_src ----
    int b = blockIdx.x - NBUCK;
    int nbase = b << 9;
    int e0 = base_s[b], e1 = base_s[b + 1];
    sdeg[t] = 0;
    sdeg[t + 256] = 0;
    __syncthreads();
    for (int e = e0 + t; e < e1; e += 256) atomicAdd(&sdeg[locs[e]], 1);
    __syncthreads();
#pragma unroll
    for (int half = 0; half < 2; ++half) {
      int j = t + half * 256;
      int node = nbase + j;
      if (node < N_NODES) {
        int d = sdeg[j];
        norm_src[node] = rsqrtf((float)(d > 1 ? d : 1));
      }
    }
    return;
  }
  // ---- dst side ----
  int b = blockIdx.x;
  int nbase = b << 9;
  int e0 = base_d[b], e1 = base_d[b + 1];
  sdeg[t] = 0;
  sdeg[t + 256] = 0;
  __syncthreads();
  for (int e = e0 + t; e < e1; e += 256) atomicAdd(&sdeg[packed[e] >> 17], 1);
  __syncthreads();
  sinc[t] = sdeg[t];
  sinc[t + 256] = sdeg[t + 256];
  __syncthreads();
  for (int off = 1; off < 512; off <<= 1) {
    int a0 = (t >= off) ? sinc[t - off] : 0;
    int i1 = t + 256;
    int a1 = (i1 >= off) ? sinc[i1 - off] : 0;
    __syncthreads();
    sinc[t] += a0;
    sinc[i1] += a1;
    __syncthreads();
  }
#pragma unroll
  for (int half = 0; half < 2; ++half) {
    int j = t + half * 256;
    int lofs = e0 + sinc[j] - sdeg[j];
    scur[j] = lofs;
    int node = nbase + j;
    if (node < N_NODES) {
      row_start[node] = lofs;
      int d = sdeg[j];
      norm_dst[node] = rsqrtf((float)(d > 1 ? d : 1));
    }
  }
  __syncthreads();
  for (int e = e0 + t; e < e1; e += 256) {
    int p = packed[e];
    int slot = atomicAdd(&scur[p >> 17], 1);
    csr_src[slot] = p & 0x1FFFF;
  }
}

// ---------------- W pre-swizzle (all 5 matrices, one launch) ----------------
__global__ __launch_bounds__(256) void wswz_k(const float* __restrict__ W_embed,
                                              const float* __restrict__ W_layers,
                                              __half* __restrict__ Bsw) {
  int m = blockIdx.x >> 3, ct = blockIdx.x & 7;  // m: 0=embed, 1..4=layers
  const float* Wm =
      (m == 0) ? W_embed : (W_layers + (size_t)(m - 1) * 16384);
  int ks = threadIdx.x >> 6, lane = threadIdx.x & 63;
  int n = ct * 16 + (lane & 15);
  int k0 = ks * 32 + (lane >> 4) * 8;
  __half* o = Bsw + ((((size_t)m * 8 + ct) * 4 + ks) * 64 + lane) * 8;
#pragma unroll
  for (int j = 0; j < 8; ++j) o[j] = __float2half(Wm[(k0 + j) * 128 + n]);
}

// ---------------- MFMA core: wave w computes 16 rows x 128 cols ----------
// C layout per 16x16 tile: row = quad*4 + reg, col = ct*16 + lrow.
__device__ inline void mfma_core16(const __half* sA,
                                   const __half* __restrict__ Bsw,
                                   floatx4 (&acc)[8], int w, int lane,
                                   int quad, int lrow) {
#pragma unroll
  for (int ct = 0; ct < 8; ++ct) acc[ct] = (floatx4)(0.f);
#pragma unroll
  for (int ks = 0; ks < 4; ++ks) {
    int m = w * 16 + lrow;
    half8 afrag = *(const half8*)(&sA[m * 136 + ks * 32 + quad * 8]);
#pragma unroll
    for (int ct = 0; ct < 8; ++ct) {
      half8 bfrag = *(const half8*)(&Bsw[(((size_t)ct * 4 + ks) * 64 + lane) * 8]);
      acc[ct] = __builtin_amdgcn_mfma_f32_16x16x32_f16(afrag, bfrag, acc[ct],
                                                       0, 0, 0);
    }
  }
}

// ---------------- fp8 accumulate helper (8 cols / lane) ----------------
__device__ inline void accf8x8(float (&a)[8], uint2 v) {
  floatx2 f;
  f = __builtin_amdgcn_cvt_pk_f32_fp8(v.x, false); a[0] += f.x; a[1] += f.y;
  f = __builtin_amdgcn_cvt_pk_f32_fp8(v.x, true);  a[2] += f.x; a[3] += f.y;
  f = __builtin_amdgcn_cvt_pk_f32_fp8(v.y, false); a[4] += f.x; a[5] += f.y;
  f = __builtin_amdgcn_cvt_pk_f32_fp8(v.y, true);  a[6] += f.x; a[7] += f.y;
}

// ---------------- embed GEMM: A16 = fp16(h @ W + b); S8 = fp8(.*ns) ------
// Epilogue: fp32 C staged to LDS in two 32-row rounds -> coalesced stores.
// S8 written SLAB-MAJOR: slab = col>>5, word (row*32 + (col&31))/4.
__global__ __launch_bounds__(256) void mfma_gemm_f32in(
    const float* __restrict__ X32, const __half* __restrict__ Bsw,
    const float* __restrict__ bias, __half* __restrict__ A16,
    unsigned char* __restrict__ S8, const float* __restrict__ norm_src) {
  __shared__ __half sA[64 * 136];  // 17.4 KB; reused as fp32 C half-tile
  const int tid = threadIdx.x;
  const int w = tid >> 6, lane = tid & 63;
  const int quad = lane >> 4, lrow = lane & 15;
  const int row_base = blockIdx.x * 64;

  // stage fp32 tile -> fp16 LDS (2048 float4 reads)
#pragma unroll
  for (int i = 0; i < 8; ++i) {
    int g = i * 256 + tid;
    int r = g >> 5, q = g & 31;
    int row = row_base + r;
    float4 v = make_float4(0.f, 0.f, 0.f, 0.f);
    if (row < N_NODES) v = ((const float4*)X32)[(size_t)row * 32 + q];
    union { __half2 h[2]; float f[2]; } u;
    u.h[0] = __floats2half2_rn(v.x, v.y);
    u.h[1] = __floats2half2_rn(v.z, v.w);
    *(float2*)(&sA[r * 136 + q * 4]) = *(float2*)u.f;
  }
  __syncthreads();

  floatx4 acc[8];
  mfma_core16(sA, Bsw, acc, w, lane, quad, lrow);

  float bcol[8];
#pragma unroll
  for (int ct = 0; ct < 8; ++ct) bcol[ct] = bias[ct * 16 + lrow];

  float* sC = (float*)sA;  // [32][132] fp32 (16896 B <= 17408 B)
#pragma unroll
  for (int h = 0; h < 2; ++h) {
    __syncthreads();  // h=0: all mfma LDS reads done; h=1: readback done
    if ((w >> 1) == h) {
      int hw = w & 1;
#pragma unroll
      for (int ct = 0; ct < 8; ++ct)
#pragma unroll
        for (int reg = 0; reg < 4; ++reg)
          sC[(hw * 16 + quad * 4 + reg) * 132 + ct * 16 + lrow] =
              acc[ct][reg] + bcol[ct];
    }
    __syncthreads();
#pragma unroll
    for (int k = 0; k < 4; ++k) {
      int c = k * 256 + tid;       // chunk 0..1023 (16B of fp32 each)
      int hr = c >> 5;             // 0..31
      int col = (c & 31) * 4;
      int row = row_base + h * 32 + hr;
      if (row < N_NODES) {
        float4 y = *(const float4*)&sC[hr * 132 + col];
        union { __half2 hh[2]; float2 f; } u;
        u.hh[0] = __floats2half2_rn(y.x, y.y);
        u.hh[1] = __floats2half2_rn(y.z, y.w);
        *(float2*)(A16 + (size_t)row * 128 + col) = u.f;
        float ns = norm_src[row];
        unsigned pb = 0;
        pb = __builtin_amdgcn_cvt_pk_fp8_f32(y.x * ns, y.y * ns, pb, false);
        pb = __builtin_amdgcn_cvt_pk_fp8_f32(y.z * ns, y.w * ns, pb, true);
        // slab-major: slab = col>>5, 4B word index within slab
        ((unsigned*)S8)[(size_t)(col >> 5) * (N_NODES * 8) + row * 8 +
                        ((col & 31) >> 2)] = pb;
      }
    }
  }
}

// ---------------- slabbed gather: 4 lanes/node/slab, L2-resident slabs ----
// Slab = 32 cols (3.2 MB < 4 MB per-XCD L2). Lane l4 owns cols
// slab*32 + l4*8 (uint2). Edge order per column unchanged -> numerics
// identical. Plain loads (R19's nontemporal flag defeated L2 caching).
__global__ __launch_bounds__(256, 8) void gather4_k(
    const uint2* __restrict__ Hs, const int* __restrict__ row_start,
    const int* __restrict__ csr_src, const float* __restrict__ norm_dst,
    __half* __restrict__ out) {
  int node = (blockIdx.x * 256 + threadIdx.x) >> 2;
  int l4 = threadIdx.x & 3;
  if (node >= N_NODES) return;
  int s0 = row_start[node], s1 = row_start[node + 1];
  int deg = s1 - s0;
  int nfull = deg >> 3;
  float nd = norm_dst[node];
#pragma unroll 1
  for (int slab = 0; slab < 4; ++slab) {
    const uint2* Hsl = Hs + (size_t)slab * SLABQ;
    float a[8];
#pragma unroll
    for (int i = 0; i < 8; ++i) a[i] = 0.f;
    int e = s0;
    if (nfull) {
      int idxA = csr_src[e + l4];
      int idxB = csr_src[e + 4 + l4];
      for (int k = 0; k < nfull; ++k) {
        uint2 v0 = Hsl[(size_t)__shfl(idxA, 0, 4) * 4 + l4];
        uint2 v1 = Hsl[(size_t)__shfl(idxA, 1, 4) * 4 + l4];
        uint2 v2 = Hsl[(size_t)__shfl(idxA, 2, 4) * 4 + l4];
        uint2 v3 = Hsl[(size_t)__shfl(idxA, 3, 4) * 4 + l4];
        uint2 v4 = Hsl[(size_t)__shfl(idxB, 0, 4) * 4 + l4];
        uint2 v5 = Hsl[(size_t)__shfl(idxB, 1, 4) * 4 + l4];
        uint2 v6 = Hsl[(size_t)__shfl(idxB, 2, 4) * 4 + l4];
        uint2 v7 = Hsl[(size_t)__shfl(idxB, 3, 4) * 4 + l4];
        // prefetch next chunk's indices (clamped; unused on last iter)
        int pa = e + 8 + l4, pb = e + 12 + l4;
        int idxA_n = csr_src[pa < N_EDGES ? pa : (N_EDGES - 1)];
        int idxB_n = csr_src[pb < N_EDGES ? pb : (N_EDGES - 1)];
        accf8x8(a, v0); accf8x8(a, v1); accf8x8(a, v2); accf8x8(a, v3);
        accf8x8(a, v4); accf8x8(a, v5); accf8x8(a, v6); accf8x8(a, v7);
        idxA = idxA_n;
        idxB = idxB_n;
        e += 8;
      }
    }
    int cnt = s1 - e;
    if (cnt) {
      int iA = (l4 < cnt) ? csr_src[e + l4] : 0;
      int iB = (4 + l4 < cnt) ? csr_src[e + 4 + l4] : 0;
      int jm = cnt < 4 ? cnt : 4;
      for (int j = 0; j < jm; ++j)
        accf8x8(a, Hsl[(size_t)__shfl(iA, j, 4) * 4 + l4]);
      for (int j = 4; j < cnt; ++j)
        accf8x8(a, Hsl[(size_t)__shfl(iB, j - 4, 4) * 4 + l4]);
    }
    union { __half2 hh[4]; float4 f; } u;
#pragma unroll
    for (int q = 0; q < 4; ++q)
      u.hh[q] = __floats2half2_rn(a[2 * q] * nd, a[2 * q + 1] * nd);
    *(float4*)(out + (size_t)node * 128 + slab * 32 + l4 * 8) = u.f;
  }
}

// ---------------- layer GEMM: hl16 = fp16(agg16 @ W + b) + BN stats -------
__global__ __launch_bounds__(256) void mfma_gemm_f16(
    const __half* __restrict__ X16, const __half* __restrict__ Bsw,
    const float* __restrict__ bias, __half* __restrict__ hl16,
    float* __restrict__ stats) {
  __shared__ __half sA[64 * 136];  // A-tile fp16; reused as fp32 C half-tile
  __shared__ float sred[1024];     // cross-wave stats scratch
  const int tid = threadIdx.x;
  const int w = tid >> 6, lane = tid & 63;
  const int quad = lane >> 4, lrow = lane & 15;
  const int row_base = blockIdx.x * 64;

  // stage fp16 tile (1024 float4 reads)
#pragma unroll
  for (int i = 0; i < 4; ++i) {
    int g = i * 256 + tid;
    int r = g >> 4, p = g & 15;
    int row = row_base + r;
    float4 v = make_float4(0.f, 0.f, 0.f, 0.f);
    if (row < N_NODES) v = ((const float4*)X16)[(size_t)row * 16 + p];
    *(float4*)(&sA[r * 136 + p * 8]) = v;
  }
  __syncthreads();

  floatx4 acc[8];
  mfma_core16(sA, Bsw, acc, w, lane, quad, lrow);

  // ---- BN stats from fp32 registers ----
  float bcol[8], psum[8], pqsum[8];
#pragma unroll
  for (int ct = 0; ct < 8; ++ct) {
    bcol[ct] = bias[ct * 16 + lrow];
    psum[ct] = 0.f;
    pqsum[ct] = 0.f;
#pragma unroll
    for (int reg = 0; reg < 4; ++reg) {
      int row = row_base + w * 16 + quad * 4 + reg;
      if (row < N_NODES) {
        float y = acc[ct][reg] + bcol[ct];
        psum[ct] += y;
        pqsum[ct] += y * y;
      }
    }
  }
#pragma unroll
  for (int ct = 0; ct < 8; ++ct) {
    psum[ct] += __shfl_xor(psum[ct], 16, 64);
    psum[ct] += __shfl_xor(psum[ct], 32, 64);
    pqsum[ct] += __shfl_xor(pqsum[ct], 16, 64);
    pqsum[ct] += __shfl_xor(pqsum[ct], 32, 64);
  }
  if (quad == 0) {
#pragma unroll
    for (int ct = 0; ct < 8; ++ct) {
      sred[w * 128 + ct * 16 + lrow] = psum[ct];
      sred[512 + w * 128 + ct * 16 + lrow] = pqsum[ct];
    }
  }
  __syncthreads();
  if (tid < 128) {
    float s = sred[tid] + sred[128 + tid] + sred[256 + tid] + sred[384 + tid];
    float q = sred[512 + tid] + sred[640 + tid] + sred[768 + tid] +
              sred[896 + tid];
    float* st = stats + (size_t)(blockIdx.x & (SREP - 1)) * 256;
    atomicAdd(&st[tid], s);
    atomicAdd(&st[128 + tid], q);
  }

  // ---- coalesced hl16 store via fp32 LDS transpose ----
  float* sC = (float*)sA;  // [32][132] fp32
#pragma unroll
  for (int h = 0; h < 2; ++h) {
    __syncthreads();  // h=0: mfma reads + stats barrier done; h=1: readback done
    if ((w >> 1) == h) {
      int hw = w & 1;
#pragma unroll
      for (int ct = 0; ct < 8; ++ct)
#pragma unroll
        for (int reg = 0; reg < 4; ++reg)
          sC[(hw * 16 + quad * 4 + reg) * 132 + ct * 16 + lrow] =
              acc[ct][reg] + bcol[ct];
    }
    __syncthreads();
#pragma unroll
    for (int k = 0; k < 4; ++k) {
      int c = k * 256 + tid;
      int hr = c >> 5;
      int col = (c & 31) * 4;
      int row = row_base + h * 32 + hr;
      if (row < N_NODES) {
        float4 y = *(const float4*)&sC[hr * 132 + col];
        union { __half2 hh[2]; float2 f; } u;
        u.hh[0] = __floats2half2_rn(y.x, y.y);
        u.hh[1] = __floats2half2_rn(y.z, y.w);
        *(float2*)(hl16 + (size_t)row * 128 + col) = u.f;
      }
    }
  }
}

// ---------------- BN finalize: collapse SREP replicas -> sc_sh ----------
__global__ __launch_bounds__(128) void bn_fin_k(const float* __restrict__ stats,
                                                const float* __restrict__ gamma,
                                                const float* __restrict__ beta,
                                                float* __restrict__ sc_sh) {
  int c = threadIdx.x;
  float s = 0.f, q = 0.f;
  for (int r = 0; r < SREP; ++r) {
    s += stats[r * 256 + c];
    q += stats[r * 256 + 128 + c];
  }
  const float invn = 1.0f / (float)N_NODES;
  float mean = s * invn;
  float var = q * invn - mean * mean;
  var = fmaxf(var, 0.f);
  float sc = gamma[c] * rsqrtf(var + BN_EPS);
  sc_sh[c] = sc;
  sc_sh[128 + c] = beta[c] - mean * sc;
}

// ---------------- BN apply + ReLU + residual ----------------
// S8 written SLAB-MAJOR: slab = c8>>2, uint2 slot node*4 + (c8&3).
__global__ __launch_bounds__(256) void bnrelu_k(
    const __half* __restrict__ hl16, __half* __restrict__ A16,
    unsigned char* __restrict__ S8, const float* __restrict__ sc_sh,
    const float* __restrict__ norm_src, int write_scaled) {
  int idx = blockIdx.x * 256 + threadIdx.x;  // < N_NODES*16
  int node = idx >> 4;
  int c8 = idx & 15;
  float4 hv4 = *(const float4*)(hl16 + (size_t)idx * 8);
  float4 av4 = *(const float4*)(A16 + (size_t)idx * 8);
  const __half2* hp = (const __half2*)&hv4;
  const __half2* ap = (const __half2*)&av4;
  const float4* sv = (const float4*)sc_sh;
  float4 s0 = sv[c8 * 2], s1 = sv[c8 * 2 + 1];
  float4 b0 = sv[32 + c8 * 2], b1 = sv[32 + c8 * 2 + 1];
  float n = write_scaled ? norm_src[node] : 0.f;
  float2 f0 = __half22float2(hp[0]), f1 = __half22float2(hp[1]);
  float2 f2 = __half22float2(hp[2]), f3 = __half22float2(hp[3]);
  float2 a0 = __half22float2(ap[0]), a1 = __half22float2(ap[1]);
  float2 a2 = __half22float2(ap[2]), a3 = __half22float2(ap[3]);
  float v[8];
  v[0] = fmaxf(f0.x * s0.x + b0.x, 0.f) + a0.x;
  v[1] = fmaxf(f0.y * s0.y + b0.y, 0.f) + a0.y;
  v[2] = fmaxf(f1.x * s0.z + b0.z, 0.f) + a1.x;
  v[3] = fmaxf(f1.y * s0.w + b0.w, 0.f) + a1.y;
  v[4] = fmaxf(f2.x * s1.x + b1.x, 0.f) + a2.x;
  v[5] = fmaxf(f2.y * s1.y + b1.y, 0.f) + a2.y;
  v[6] = fmaxf(f3.x * s1.z + b1.z, 0.f) + a3.x;
  v[7] = fmaxf(f3.y * s1.w + b1.w, 0.f) + a3.y;
  union { __half2 h[4]; float4 f; } ua;
#pragma unroll
  for (int q = 0; q < 4; ++q)
    ua.h[q] = __floats2half2_rn(v[2 * q], v[2 * q + 1]);
  *(float4*)(A16 + (size_t)idx * 8) = ua.f;
  if (write_scaled) {
    unsigned lo = 0, hi = 0;
    lo = __builtin_amdgcn_cvt_pk_fp8_f32(v[0] * n, v[1] * n, lo, false);
    lo = __builtin_amdgcn_cvt_pk_fp8_f32(v[2] * n, v[3] * n, lo, true);
    hi = __builtin_amdgcn_cvt_pk_fp8_f32(v[4] * n, v[5] * n, hi, false);
    hi = __builtin_amdgcn_cvt_pk_fp8_f32(v[6] * n, v[7] * n, hi, true);
    ((uint2*)S8)[(size_t)(c8 >> 2) * SLABQ + node * 4 + (c8 & 3)] =
        make_uint2(lo, hi);
  }
}

// ---------------- readout ----------------
__global__ __launch_bounds__(128) void gsum_k(const __half* __restrict__ A16,
                                              const int* __restrict__ gid,
                                              float* gsum) {
  int c = threadIdx.x;
  int n0 = blockIdx.x * 128;
  int n1 = n0 + 128;
  if (n1 > N_NODES) n1 = N_NODES;
  int cur = gid[n0];
  float local = 0.f;
  for (int n = n0; n < n1; ++n) {
    int g = gid[n];  // sorted: few changes per block
    if (g != cur) {
      atomicAdd(&gsum[cur * 128 + c], local);
      local = 0.f;
      cur = g;
    }
    local += __half2float(A16[(size_t)n * 128 + c]);
  }
  atomicAdd(&gsum[cur * 128 + c], local);
}

// gout with inline graph-bounds binary search.
__global__ __launch_bounds__(128) void gout_k(const float* __restrict__ gsum,
                                              const int* __restrict__ gid,
                                              float* __restrict__ out) {
  __shared__ int bnd[2];
  int g = blockIdx.x, c = threadIdx.x;
  if (c < 2) {
    int target = g + c;
    int lo = 0, hi = N_NODES;
    while (lo < hi) {
      int mid = (lo + hi) >> 1;
      if (gid[mid] < target) lo = mid + 1; else hi = mid;
    }
    bnd[c] = lo;
  }
  __syncthreads();
  float cnt = (float)(bnd[1] - bnd[0]);
  if (cnt < 1.f) cnt = 1.f;
  out[g * 128 + c] = gsum[g * 128 + c] / cnt;
}

// ---------------- launch ----------------
extern "C" void kernel_launch(void* const* d_in, const int* in_sizes, int n_in,
                              void* d_out, int out_size, void* d_ws,
                              size_t ws_size, hipStream_t stream) {
  const float* h = (const float*)d_in[0];
  const int* src = (const int*)d_in[1];
  const int* dst = (const int*)d_in[2];
  const int* gid = (const int*)d_in[3];
  const float* W_embed = (const float*)d_in[4];
  const float* b_embed = (const float*)d_in[5];
  const float* W_layers = (const float*)d_in[6];
  const float* b_layers = (const float*)d_in[7];
  const float* gamma = (const float*)d_in[8];
  const float* beta = (const float*)d_in[9];
  float* out = (float*)d_out;
  (void)in_sizes; (void)n_in; (void)out_size; (void)ws_size;

  char* ws = (char*)d_ws;
  size_t o = 0;
  auto alloc = [&](size_t bytes) -> char* {
    char* p = ws + o;
    o = (o + bytes + 255) & ~(size_t)255;
    return p;
  };
  int* cnt_d = (int*)alloc(NBUCK * 4);  // zeroed (one memset w/ cnt_s)
  int* cnt_s = (int*)alloc(NBUCK * 4);
  int* base_d = (int*)alloc((NBUCK + 1) * 4);
  int* cur_d = (int*)alloc(NBUCK * 4);
  int* base_s = (int*)alloc((NBUCK + 1) * 4);
  int* cur_s = (int*)alloc(NBUCK * 4);
  int* bh_d = (int*)alloc((size_t)256 * NBUCK * 4);
  int* bh_s = (int*)alloc((size_t)256 * NBUCK * 4);
  float* norm_src = (float*)alloc(N_NODES * 4);
  float* norm_dst = (float*)alloc(N_NODES * 4);
  int* row_start = (int*)alloc((N_NODES + 1) * 4);
  int* csr_src = (int*)alloc((size_t)N_EDGES * 4);
  int* packed = (int*)alloc((size_t)N_EDGES * 4);
  unsigned short* locs = (unsigned short*)alloc((size_t)N_EDGES * 2);
  float* stats4 = (float*)alloc((size_t)N_LAYERS * SREP * 256 * 4);
  float* gsum = (float*)alloc(N_GRAPHS * 128 * 4);  // adjacent to stats4
  float* sc_sh = (float*)alloc(256 * 4);
  __half* Bsw = (__half*)alloc(5 * 16384 * 2);
  __half* A16 = (__half*)alloc((size_t)N_NODES * 128 * 2);  // residual (fp16)
  unsigned char* P0f8 = (unsigned char*)alloc((size_t)N_NODES * 128);  // fp8, slab-major
  __half* P1h = (__half*)alloc((size_t)N_NODES * 128 * 2);  // agg (fp16)
  __half* H16 = (__half*)alloc((size_t)N_NODES * 128 * 2);  // hl (fp16)

  // zero bucket counters; zero all per-layer stats replicas + gsum
  hipMemsetAsync(cnt_d, 0, 2048, stream);
  hipMemsetAsync(stats4, 0, (size_t)N_LAYERS * SREP * 256 * 4 + 65536, stream);

  // ---- radix CSR build ----
  binA_k<<<256, 256, 0, stream>>>(src, dst, cnt_d, cnt_s, bh_d, bh_s);
  scan196_k<<<1, 256, 0, stream>>>(cnt_d, cnt_s, base_d, cur_d, base_s, cur_s,
                                   row_start);
  scat_k<<<256, 256, 0, stream>>>(src, dst, cur_d, cur_s, bh_d, bh_s, packed,
                                  locs);
  cdcs_k<<<2 * NBUCK, 256, 0, stream>>>(base_d, packed, row_start, csr_src,
                                        norm_dst, base_s, locs, norm_src);

  wswz_k<<<40, 256, 0, stream>>>(W_embed, W_layers, Bsw);

  // embed: A16 = fp16(h @ W_embed + b) ; P0f8 = fp8(. * norm_src), slab-major
  mfma_gemm_f32in<<<(N_NODES + 63) / 64, 256, 0, stream>>>(
      h, Bsw, b_embed, A16, P0f8, norm_src);

  for (int l = 0; l < N_LAYERS; ++l) {
    float* stats = stats4 + (size_t)l * SREP * 256;
    gather4_k<<<(N_NODES * 4 + 255) / 256, 256, 0, stream>>>(
        (const uint2*)P0f8, row_start, csr_src, norm_dst, P1h);
    mfma_gemm_f16<<<(N_NODES + 63) / 64, 256, 0, stream>>>(
        P1h, Bsw + (size_t)(1 + l) * 16384, b_layers + l * DIM, H16, stats);
    bn_fin_k<<<1, 128, 0, stream>>>(stats, gamma + l * DIM, beta + l * DIM,
                                    sc_sh);
    bnrelu_k<<<(N_NODES * 16 + 255) / 256, 256, 0, stream>>>(
        H16, A16, P0f8, sc_sh, norm_src, (l < N_LAYERS - 1) ? 1 : 0);
  }

  gsum_k<<<(N_NODES + 127) / 128, 128, 0, stream>>>(A16, gid, gsum);
  gout_k<<<N_GRAPHS, 128, 0, stream>>>(gsum, gid, out);
}

// Round 9
// 560.826 us; speedup vs baseline: 1.6167x; 1.1490x over previous
//
#include <hip/hip_runtime.h>
#include <hip/hip_bf16.h>
#include <hip/hip_fp16.h>

// GCN forward. fp16 inter-layer tensors; gather operand fp8 e4m3 (one
// 128B cache line per row); fp32 accum everywhere.
// R3: MFMA GEMM, pre-swizzled W. R7: radix-bucketed CSR build.
// R8: 64-row GEMM tiles; fp16 residual. R10: fp8 gather operand.
// R11: BN stats 64x-replicated. R12: uint-vector gather, persisted
//     histograms, fused norms. R13: coalesced GEMM epilogues (LDS xpose).
// R15: de-fused gather, 16 lanes/node uint2, launch_bounds(256,8).
// R16: index-prefetch pipeline; merged cdcs_k.
// R18-R20: slab-major gather experiment FAILED (4x L2 transactions per
//     edge: 32B used of each 128B line; nt-loads also defeated L2).
//     Row-major = 1 fully-consumed line per edge is the transaction
//     floor (~1.6M 128B random reads/layer ~= 32 us). REVERTED.
// R21: launch-count reduction, 24 -> 17 dispatches (suspected ~6 us/gap):
//     wswz merged into binA grid (blocks >= 256); scan196 in binA's last
//     block; bn_fin in layer-GEMM's last block; gout in gsum's last
//     block. Last-block pattern: syncthreads (drains vmcnt) -> atomic
//     counter -> threadfence. Numerics unchanged.

#define N_NODES 100000
#define N_EDGES 1600000
#define N_GRAPHS 128
#define DIM 128
#define N_LAYERS 4
#define BN_EPS 1e-5f
#define NBUCK 196          // ceil(N_NODES/512)
#define EPB 6250           // edges per block in bin/scatter passes (256 blocks)
#define SREP 64            // stats replicas (atomic-chain 1563 -> ~24)

typedef __attribute__((ext_vector_type(8))) _Float16 half8;
typedef __attribute__((ext_vector_type(4))) float floatx4;
typedef __attribute__((ext_vector_type(2))) float floatx2;

// ---------------- pass A: bucket counts + per-block histograms,
//                  + wswz (blocks >= 256) + scan196 (last binA block) ----
__global__ __launch_bounds__(256) void binA_k(
    const int* __restrict__ src, const int* __restrict__ dst,
    int* __restrict__ cnt_d, int* __restrict__ cnt_s,
    int* __restrict__ bh_d, int* __restrict__ bh_s,
    int* __restrict__ base_d, int* __restrict__ cur_d,
    int* __restrict__ base_s, int* __restrict__ cur_s,
    int* __restrict__ row_start, const float* __restrict__ W_embed,
    const float* __restrict__ W_layers, __half* __restrict__ Bsw,
    int* __restrict__ ctr) {
  __shared__ int hd[NBUCK], hs[NBUCK];
  __shared__ int sd[256], ss[256];
  __shared__ int lastf;
  int t = threadIdx.x;

  if (blockIdx.x >= 256) {  // ---- W pre-swizzle (40 blocks) ----
    int b = blockIdx.x - 256;
    int m = b >> 3, ct = b & 7;  // m: 0=embed, 1..4=layers
    const float* Wm = (m == 0) ? W_embed : (W_layers + (size_t)(m - 1) * 16384);
    int ks = t >> 6, lane = t & 63;
    int n = ct * 16 + (lane & 15);
    int k0 = ks * 32 + (lane >> 4) * 8;
    __half* o = Bsw + ((((size_t)m * 8 + ct) * 4 + ks) * 64 + lane) * 8;
#pragma unroll
    for (int j = 0; j < 8; ++j) o[j] = __float2half(Wm[(k0 + j) * 128 + n]);
    return;
  }

  for (int i = t; i < NBUCK; i += 256) { hd[i] = 0; hs[i] = 0; }
  __syncthreads();
  int e0 = blockIdx.x * EPB;
  for (int e = e0 + t; e < e0 + EPB; e += 256) {
    atomicAdd(&hd[dst[e] >> 9], 1);
    atomicAdd(&hs[src[e] >> 9], 1);
  }
  __syncthreads();
  for (int i = t; i < NBUCK; i += 256) {
    int v = hd[i], v2 = hs[i];
    bh_d[blockIdx.x * NBUCK + i] = v;
    bh_s[blockIdx.x * NBUCK + i] = v2;
    if (v) atomicAdd(&cnt_d[i], v);
    if (v2) atomicAdd(&cnt_s[i], v2);
  }
  __syncthreads();  // drains the atomics (vmcnt(0) before barrier)
  if (t == 0) lastf = (atomicAdd(ctr, 1) == 255) ? 1 : 0;
  __syncthreads();
  if (lastf) {  // ---- inline scan196 ----
    __threadfence();
    int vd = (t < NBUCK) ? cnt_d[t] : 0;
    int vs = (t < NBUCK) ? cnt_s[t] : 0;
    sd[t] = vd;
    ss[t] = vs;
    __syncthreads();
    for (int off = 1; off < 256; off <<= 1) {
      int ad = (t >= off) ? sd[t - off] : 0;
      int as = (t >= off) ? ss[t - off] : 0;
      __syncthreads();
      sd[t] += ad;
      ss[t] += as;
      __syncthreads();
    }
    if (t < NBUCK) {
      base_d[t] = sd[t] - vd;
      cur_d[t] = sd[t] - vd;
      base_s[t] = ss[t] - vs;
      cur_s[t] = ss[t] - vs;
    }
    if (t == 0) {
      base_d[NBUCK] = N_EDGES;
      base_s[NBUCK] = N_EDGES;
      row_start[N_NODES] = N_EDGES;
    }
  }
}

// ---------------- pass B: scatter edges into bucket regions ----------------
__global__ __launch_bounds__(256) void scat_k(
    const int* __restrict__ src, const int* __restrict__ dst,
    int* __restrict__ cur_d, int* __restrict__ cur_s,
    const int* __restrict__ bh_d, const int* __restrict__ bh_s,
    int* __restrict__ packed, unsigned short* __restrict__ locs) {
  __shared__ int hd[NBUCK], hs[NBUCK];
  int t = threadIdx.x;
  for (int i = t; i < NBUCK; i += 256) {
    hd[i] = bh_d[blockIdx.x * NBUCK + i];
    hs[i] = bh_s[blockIdx.x * NBUCK + i];
  }
  __syncthreads();
  if (t < NBUCK) {  // claim chunks; hd/hs become running cursors
    hd[t] = atomicAdd(&cur_d[t], hd[t]);
    hs[t] = atomicAdd(&cur_s[t], hs[t]);
  }
  __syncthreads();
  int e0 = blockIdx.x * EPB;
  for (int e = e0 + t; e < e0 + EPB; e += 256) {
    int s = src[e], d = dst[e];
    int slot = atomicAdd(&hd[d >> 9], 1);
    packed[slot] = ((d & 511) << 17) | s;
    int slot2 = atomicAdd(&hs[s >> 9], 1);
    locs[slot2] = (unsigned short)(s & 511);
  }
}

// ---------------- pass C (merged): dst CSR fill + norms ----------------
__global__ __launch_bounds__(256) void cdcs_k(
    const int* __restrict__ base_d, const int* __restrict__ packed,
    int* __restrict__ row_start, int* __restrict__ csr_src,
    float* __restrict__ norm_dst, const int* __restrict__ base_s,
    const unsigned short* __restrict__ locs, float* __restrict__ norm_src) {
  __shared__ int sdeg[512], sinc[512], scur[512];
  int t = threadIdx.x;
  if (blockIdx.x >= NBUCK) {  // ---- src-degree histogram -> norm_src ----
    int b = blockIdx.x - NBUCK;
    int nbase = b << 9;
    int e0 = base_s[b], e1 = base_s[b + 1];
    sdeg[t] = 0;
    sdeg[t + 256] = 0;
    __syncthreads();
    for (int e = e0 + t; e < e1; e += 256) atomicAdd(&sdeg[locs[e]], 1);
    __syncthreads();
#pragma unroll
    for (int half = 0; half < 2; ++half) {
      int j = t + half * 256;
      int node = nbase + j;
      if (node < N_NODES) {
        int d = sdeg[j];
        norm_src[node] = rsqrtf((float)(d > 1 ? d : 1));
      }
    }
    return;
  }
  // ---- dst side ----
  int b = blockIdx.x;
  int nbase = b << 9;
  int e0 = base_d[b], e1 = base_d[b + 1];
  sdeg[t] = 0;
  sdeg[t + 256] = 0;
  __syncthreads();
  for (int e = e0 + t; e < e1; e += 256) atomicAdd(&sdeg[packed[e] >> 17], 1);
  __syncthreads();
  sinc[t] = sdeg[t];
  sinc[t + 256] = sdeg[t + 256];
  __syncthreads();
  for (int off = 1; off < 512; off <<= 1) {
    int a0 = (t >= off) ? sinc[t - off] : 0;
    int i1 = t + 256;
    int a1 = (i1 >= off) ? sinc[i1 - off] : 0;
    __syncthreads();
    sinc[t] += a0;
    sinc[i1] += a1;
    __syncthreads();
  }
#pragma unroll
  for (int half = 0; half < 2; ++half) {
    int j = t + half * 256;
    int lofs = e0 + sinc[j] - sdeg[j];
    scur[j] = lofs;
    int node = nbase + j;
    if (node < N_NODES) {
      row_start[node] = lofs;
      int d = sdeg[j];
      norm_dst[node] = rsqrtf((float)(d > 1 ? d : 1));
    }
  }
  __syncthreads();
  for (int e = e0 + t; e < e1; e += 256) {
    int p = packed[e];
    int slot = atomicAdd(&scur[p >> 17], 1);
    csr_src[slot] = p & 0x1FFFF;
  }
}

// ---------------- MFMA core: wave w computes 16 rows x 128 cols ----------
// C layout per 16x16 tile: row = quad*4 + reg, col = ct*16 + lrow.
__device__ inline void mfma_core16(const __half* sA,
                                   const __half* __restrict__ Bsw,
                                   floatx4 (&acc)[8], int w, int lane,
                                   int quad, int lrow) {
#pragma unroll
  for (int ct = 0; ct < 8; ++ct) acc[ct] = (floatx4)(0.f);
#pragma unroll
  for (int ks = 0; ks < 4; ++ks) {
    int m = w * 16 + lrow;
    half8 afrag = *(const half8*)(&sA[m * 136 + ks * 32 + quad * 8]);
#pragma unroll
    for (int ct = 0; ct < 8; ++ct) {
      half8 bfrag = *(const half8*)(&Bsw[(((size_t)ct * 4 + ks) * 64 + lane) * 8]);
      acc[ct] = __builtin_amdgcn_mfma_f32_16x16x32_f16(afrag, bfrag, acc[ct],
                                                       0, 0, 0);
    }
  }
}

// ---------------- fp8 accumulate helper (8 cols / lane) ----------------
__device__ inline void accf8x8(float (&a)[8], uint2 v) {
  floatx2 f;
  f = __builtin_amdgcn_cvt_pk_f32_fp8(v.x, false); a[0] += f.x; a[1] += f.y;
  f = __builtin_amdgcn_cvt_pk_f32_fp8(v.x, true);  a[2] += f.x; a[3] += f.y;
  f = __builtin_amdgcn_cvt_pk_f32_fp8(v.y, false); a[4] += f.x; a[5] += f.y;
  f = __builtin_amdgcn_cvt_pk_f32_fp8(v.y, true);  a[6] += f.x; a[7] += f.y;
}

// ---------------- embed GEMM: A16 = fp16(h @ W + b); S8 = fp8(.*ns) ------
// Epilogue: fp32 C staged to LDS in two 32-row rounds -> coalesced stores.
__global__ __launch_bounds__(256) void mfma_gemm_f32in(
    const float* __restrict__ X32, const __half* __restrict__ Bsw,
    const float* __restrict__ bias, __half* __restrict__ A16,
    unsigned char* __restrict__ S8, const float* __restrict__ norm_src) {
  __shared__ __half sA[64 * 136];  // 17.4 KB; reused as fp32 C half-tile
  const int tid = threadIdx.x;
  const int w = tid >> 6, lane = tid & 63;
  const int quad = lane >> 4, lrow = lane & 15;
  const int row_base = blockIdx.x * 64;

  // stage fp32 tile -> fp16 LDS (2048 float4 reads)
#pragma unroll
  for (int i = 0; i < 8; ++i) {
    int g = i * 256 + tid;
    int r = g >> 5, q = g & 31;
    int row = row_base + r;
    float4 v = make_float4(0.f, 0.f, 0.f, 0.f);
    if (row < N_NODES) v = ((const float4*)X32)[(size_t)row * 32 + q];
    union { __half2 h[2]; float f[2]; } u;
    u.h[0] = __floats2half2_rn(v.x, v.y);
    u.h[1] = __floats2half2_rn(v.z, v.w);
    *(float2*)(&sA[r * 136 + q * 4]) = *(float2*)u.f;
  }
  __syncthreads();

  floatx4 acc[8];
  mfma_core16(sA, Bsw, acc, w, lane, quad, lrow);

  float bcol[8];
#pragma unroll
  for (int ct = 0; ct < 8; ++ct) bcol[ct] = bias[ct * 16 + lrow];

  float* sC = (float*)sA;  // [32][132] fp32 (16896 B <= 17408 B)
#pragma unroll
  for (int h = 0; h < 2; ++h) {
    __syncthreads();  // h=0: all mfma LDS reads done; h=1: readback done
    if ((w >> 1) == h) {
      int hw = w & 1;
#pragma unroll
      for (int ct = 0; ct < 8; ++ct)
#pragma unroll
        for (int reg = 0; reg < 4; ++reg)
          sC[(hw * 16 + quad * 4 + reg) * 132 + ct * 16 + lrow] =
              acc[ct][reg] + bcol[ct];
    }
    __syncthreads();
#pragma unroll
    for (int k = 0; k < 4; ++k) {
      int c = k * 256 + tid;       // chunk 0..1023 (16B of fp32 each)
      int hr = c >> 5;             // 0..31
      int col = (c & 31) * 4;
      int row = row_base + h * 32 + hr;
      if (row < N_NODES) {
        float4 y = *(const float4*)&sC[hr * 132 + col];
        union { __half2 hh[2]; float2 f; } u;
        u.hh[0] = __floats2half2_rn(y.x, y.y);
        u.hh[1] = __floats2half2_rn(y.z, y.w);
        *(float2*)(A16 + (size_t)row * 128 + col) = u.f;
        float ns = norm_src[row];
        unsigned pb = 0;
        pb = __builtin_amdgcn_cvt_pk_fp8_f32(y.x * ns, y.y * ns, pb, false);
        pb = __builtin_amdgcn_cvt_pk_fp8_f32(y.z * ns, y.w * ns, pb, true);
        *(unsigned*)(S8 + (size_t)row * 128 + col) = pb;
      }
    }
  }
}

// ---------------- standalone gather: 16 lanes/node, VGPR<=64 ----------------
// Lane owns 8 cols (uint2 = 8B of the 128B row; 16 lanes cover the line).
// Software-pipelined: chunk k+1's csr_src indices issue BEFORE chunk k's
// accumulate. Per-column accumulation order unchanged -> bit-exact.
__global__ __launch_bounds__(256, 8) void gather16_k(
    const uint2* __restrict__ Hs, const int* __restrict__ row_start,
    const int* __restrict__ csr_src, const float* __restrict__ norm_dst,
    __half* __restrict__ out) {
  int node = (blockIdx.x * 256 + threadIdx.x) >> 4;
  int l16 = threadIdx.x & 15;
  int l8 = l16 & 7;
  if (node >= N_NODES) return;
  int s0 = row_start[node], s1 = row_start[node + 1];
  float a[8];
#pragma unroll
  for (int i = 0; i < 8; ++i) a[i] = 0.f;
  int deg = s1 - s0;
  int nfull = deg >> 3;
  int e = s0;
  if (nfull) {
    int idx = csr_src[e + l8];
    for (int k = 0; k < nfull; ++k) {
      uint2 v0 = Hs[(size_t)__shfl(idx, 0, 16) * 16 + l16];
      uint2 v1 = Hs[(size_t)__shfl(idx, 1, 16) * 16 + l16];
      uint2 v2 = Hs[(size_t)__shfl(idx, 2, 16) * 16 + l16];
      uint2 v3 = Hs[(size_t)__shfl(idx, 3, 16) * 16 + l16];
      uint2 v4 = Hs[(size_t)__shfl(idx, 4, 16) * 16 + l16];
      uint2 v5 = Hs[(size_t)__shfl(idx, 5, 16) * 16 + l16];
      uint2 v6 = Hs[(size_t)__shfl(idx, 6, 16) * 16 + l16];
      uint2 v7 = Hs[(size_t)__shfl(idx, 7, 16) * 16 + l16];
      // prefetch next chunk's indices (clamped; value unused on last iter)
      int pe = e + 8 + l8;
      int idx_n = csr_src[pe < N_EDGES ? pe : (N_EDGES - 1)];
      accf8x8(a, v0); accf8x8(a, v1); accf8x8(a, v2); accf8x8(a, v3);
      accf8x8(a, v4); accf8x8(a, v5); accf8x8(a, v6); accf8x8(a, v7);
      idx = idx_n;
      e += 8;
    }
  }
  int cnt = s1 - e;
  if (cnt) {
    int idx = (l8 < cnt) ? csr_src[e + l8] : 0;
    int j = 0;
    for (; j + 4 <= cnt; j += 4) {
      uint2 v0 = Hs[(size_t)__shfl(idx, j, 16) * 16 + l16];
      uint2 v1 = Hs[(size_t)__shfl(idx, j + 1, 16) * 16 + l16];
      uint2 v2 = Hs[(size_t)__shfl(idx, j + 2, 16) * 16 + l16];
      uint2 v3 = Hs[(size_t)__shfl(idx, j + 3, 16) * 16 + l16];
      accf8x8(a, v0); accf8x8(a, v1); accf8x8(a, v2); accf8x8(a, v3);
    }
    for (; j < cnt; ++j) {
      accf8x8(a, Hs[(size_t)__shfl(idx, j, 16) * 16 + l16]);
    }
  }
  float nd = norm_dst[node];
  union { __half2 hh[4]; float4 f; } u;
#pragma unroll
  for (int q = 0; q < 4; ++q)
    u.hh[q] = __floats2half2_rn(a[2 * q] * nd, a[2 * q + 1] * nd);
  *(float4*)(out + (size_t)node * 128 + l16 * 8) = u.f;
}

// ---------------- layer GEMM: hl16 = fp16(agg16 @ W + b) + BN stats;
//                  last block folds bn_fin (sc_sh) ----------------
__global__ __launch_bounds__(256) void mfma_gemm_f16(
    const __half* __restrict__ X16, const __half* __restrict__ Bsw,
    const float* __restrict__ bias, __half* __restrict__ hl16,
    float* __restrict__ stats, const float* __restrict__ gamma,
    const float* __restrict__ beta, float* __restrict__ sc_sh,
    int* __restrict__ done) {
  __shared__ __half sA[64 * 136];  // A-tile fp16; reused as fp32 C half-tile
  __shared__ float sred[1024];     // cross-wave stats scratch
  __shared__ int lastf;
  const int tid = threadIdx.x;
  const int w = tid >> 6, lane = tid & 63;
  const int quad = lane >> 4, lrow = lane & 15;
  const int row_base = blockIdx.x * 64;

  // stage fp16 tile (1024 float4 reads)
#pragma unroll
  for (int i = 0; i < 4; ++i) {
    int g = i * 256 + tid;
    int r = g >> 4, p = g & 15;
    int row = row_base + r;
    float4 v = make_float4(0.f, 0.f, 0.f, 0.f);
    if (row < N_NODES) v = ((const float4*)X16)[(size_t)row * 16 + p];
    *(float4*)(&sA[r * 136 + p * 8]) = v;
  }
  __syncthreads();

  floatx4 acc[8];
  mfma_core16(sA, Bsw, acc, w, lane, quad, lrow);

  // ---- BN stats from fp32 registers ----
  float bcol[8], psum[8], pqsum[8];
#pragma unroll
  for (int ct = 0; ct < 8; ++ct) {
    bcol[ct] = bias[ct * 16 + lrow];
    psum[ct] = 0.f;
    pqsum[ct] = 0.f;
#pragma unroll
    for (int reg = 0; reg < 4; ++reg) {
      int row = row_base + w * 16 + quad * 4 + reg;
      if (row < N_NODES) {
        float y = acc[ct][reg] + bcol[ct];
        psum[ct] += y;
        pqsum[ct] += y * y;
      }
    }
  }
#pragma unroll
  for (int ct = 0; ct < 8; ++ct) {
    psum[ct] += __shfl_xor(psum[ct], 16, 64);
    psum[ct] += __shfl_xor(psum[ct], 32, 64);
    pqsum[ct] += __shfl_xor(pqsum[ct], 16, 64);
    pqsum[ct] += __shfl_xor(pqsum[ct], 32, 64);
  }
  if (quad == 0) {
#pragma unroll
    for (int ct = 0; ct < 8; ++ct) {
      sred[w * 128 + ct * 16 + lrow] = psum[ct];
      sred[512 + w * 128 + ct * 16 + lrow] = pqsum[ct];
    }
  }
  __syncthreads();
  if (tid < 128) {
    float s = sred[tid] + sred[128 + tid] + sred[256 + tid] + sred[384 + tid];
    float q = sred[512 + tid] + sred[640 + tid] + sred[768 + tid] +
              sred[896 + tid];
    float* st = stats + (size_t)(blockIdx.x & (SREP - 1)) * 256;
    atomicAdd(&st[tid], s);
    atomicAdd(&st[128 + tid], q);
  }

  // ---- coalesced hl16 store via fp32 LDS transpose ----
  float* sC = (float*)sA;  // [32][132] fp32
#pragma unroll
  for (int h = 0; h < 2; ++h) {
    __syncthreads();  // h=0: mfma reads + stats barrier done; h=1: readback done
    if ((w >> 1) == h) {
      int hw = w & 1;
#pragma unroll
      for (int ct = 0; ct < 8; ++ct)
#pragma unroll
        for (int reg = 0; reg < 4; ++reg)
          sC[(hw * 16 + quad * 4 + reg) * 132 + ct * 16 + lrow] =
              acc[ct][reg] + bcol[ct];
    }
    __syncthreads();
#pragma unroll
    for (int k = 0; k < 4; ++k) {
      int c = k * 256 + tid;
      int hr = c >> 5;
      int col = (c & 31) * 4;
      int row = row_base + h * 32 + hr;
      if (row < N_NODES) {
        float4 y = *(const float4*)&sC[hr * 132 + col];
        union { __half2 hh[2]; float2 f; } u;
        u.hh[0] = __floats2half2_rn(y.x, y.y);
        u.hh[1] = __floats2half2_rn(y.z, y.w);
        *(float2*)(hl16 + (size_t)row * 128 + col) = u.f;
      }
    }
  }

  // ---- last block: collapse SREP replicas -> sc_sh (bn_fin folded) ----
  __syncthreads();  // drains all outstanding stores/atomics
  if (tid == 0) lastf = (atomicAdd(done, 1) == (int)gridDim.x - 1) ? 1 : 0;
  __syncthreads();
  if (lastf) {
    __threadfence();
    int c = tid;
    if (c < 128) {
      float s = 0.f, q = 0.f;
      for (int r = 0; r < SREP; ++r) {
        s += stats[r * 256 + c];
        q += stats[r * 256 + 128 + c];
      }
      const float invn = 1.0f / (float)N_NODES;
      float mean = s * invn;
      float var = q * invn - mean * mean;
      var = fmaxf(var, 0.f);
      float sc = gamma[c] * rsqrtf(var + BN_EPS);
      sc_sh[c] = sc;
      sc_sh[128 + c] = beta[c] - mean * sc;
    }
  }
}

// ---------------- BN apply + ReLU + residual ----------------
__global__ __launch_bounds__(256) void bnrelu_k(
    const __half* __restrict__ hl16, __half* __restrict__ A16,
    unsigned char* __restrict__ S8, const float* __restrict__ sc_sh,
    const float* __restrict__ norm_src, int write_scaled) {
  int idx = blockIdx.x * 256 + threadIdx.x;  // < N_NODES*16
  int node = idx >> 4;
  int c8 = idx & 15;
  float4 hv4 = *(const float4*)(hl16 + (size_t)idx * 8);
  float4 av4 = *(const float4*)(A16 + (size_t)idx * 8);
  const __half2* hp = (const __half2*)&hv4;
  const __half2* ap = (const __half2*)&av4;
  const float4* sv = (const float4*)sc_sh;
  float4 s0 = sv[c8 * 2], s1 = sv[c8 * 2 + 1];
  float4 b0 = sv[32 + c8 * 2], b1 = sv[32 + c8 * 2 + 1];
  float n = write_scaled ? norm_src[node] : 0.f;
  float2 f0 = __half22float2(hp[0]), f1 = __half22float2(hp[1]);
  float2 f2 = __half22float2(hp[2]), f3 = __half22float2(hp[3]);
  float2 a0 = __half22float2(ap[0]), a1 = __half22float2(ap[1]);
  float2 a2 = __half22float2(ap[2]), a3 = __half22float2(ap[3]);
  float v[8];
  v[0] = fmaxf(f0.x * s0.x + b0.x, 0.f) + a0.x;
  v[1] = fmaxf(f0.y * s0.y + b0.y, 0.f) + a0.y;
  v[2] = fmaxf(f1.x * s0.z + b0.z, 0.f) + a1.x;
  v[3] = fmaxf(f1.y * s0.w + b0.w, 0.f) + a1.y;
  v[4] = fmaxf(f2.x * s1.x + b1.x, 0.f) + a2.x;
  v[5] = fmaxf(f2.y * s1.y + b1.y, 0.f) + a2.y;
  v[6] = fmaxf(f3.x * s1.z + b1.z, 0.f) + a3.x;
  v[7] = fmaxf(f3.y * s1.w + b1.w, 0.f) + a3.y;
  union { __half2 h[4]; float4 f; } ua;
#pragma unroll
  for (int q = 0; q < 4; ++q)
    ua.h[q] = __floats2half2_rn(v[2 * q], v[2 * q + 1]);
  *(float4*)(A16 + (size_t)idx * 8) = ua.f;
  if (write_scaled) {
    unsigned lo = 0, hi = 0;
    lo = __builtin_amdgcn_cvt_pk_fp8_f32(v[0] * n, v[1] * n, lo, false);
    lo = __builtin_amdgcn_cvt_pk_fp8_f32(v[2] * n, v[3] * n, lo, true);
    hi = __builtin_amdgcn_cvt_pk_fp8_f32(v[4] * n, v[5] * n, hi, false);
    hi = __builtin_amdgcn_cvt_pk_fp8_f32(v[6] * n, v[7] * n, hi, true);
    ((uint2*)S8)[idx] = make_uint2(lo, hi);
  }
}

// ---------------- readout: gsum + inline gout in last block --------------
__global__ __launch_bounds__(128) void gsum_k(const __half* __restrict__ A16,
                                              const int* __restrict__ gid,
                                              float* gsum,
                                              float* __restrict__ out,
                                              int* __restrict__ done) {
  __shared__ int lastf;
  __shared__ int sbnd[129];
  int c = threadIdx.x;
  int n0 = blockIdx.x * 128;
  int n1 = n0 + 128;
  if (n1 > N_NODES) n1 = N_NODES;
  int cur = gid[n0];
  float local = 0.f;
  for (int n = n0; n < n1; ++n) {
    int g = gid[n];  // sorted: few changes per block
    if (g != cur) {
      atomicAdd(&gsum[cur * 128 + c], local);
      local = 0.f;
      cur = g;
    }
    local += __half2float(A16[(size_t)n * 128 + c]);
  }
  atomicAdd(&gsum[cur * 128 + c], local);

  __syncthreads();  // drains atomics
  if (c == 0) lastf = (atomicAdd(done, 1) == (int)gridDim.x - 1) ? 1 : 0;
  __syncthreads();
  if (lastf) {
    __threadfence();
    {  // binary search graph bound for target c
      int lo = 0, hi = N_NODES;
      while (lo < hi) {
        int mid = (lo + hi) >> 1;
        if (gid[mid] < c) lo = mid + 1; else hi = mid;
      }
      sbnd[c] = lo;
    }
    if (c == 0) sbnd[128] = N_NODES;
    __syncthreads();
    for (int g = 0; g < N_GRAPHS; ++g) {
      float cnt = (float)(sbnd[g + 1] - sbnd[g]);
      if (cnt < 1.f) cnt = 1.f;
      out[g * 128 + c] = gsum[g * 128 + c] / cnt;
    }
  }
}

// ---------------- launch ----------------
extern "C" void kernel_launch(void* const* d_in, const int* in_sizes, int n_in,
                              void* d_out, int out_size, void* d_ws,
                              size_t ws_size, hipStream_t stream) {
  const float* h = (const float*)d_in[0];
  const int* src = (const int*)d_in[1];
  const int* dst = (const int*)d_in[2];
  const int* gid = (const int*)d_in[3];
  const float* W_embed = (const float*)d_in[4];
  const float* b_embed = (const float*)d_in[5];
  const float* W_layers = (const float*)d_in[6];
  const float* b_layers = (const float*)d_in[7];
  const float* gamma = (const float*)d_in[8];
  const float* beta = (const float*)d_in[9];
  float* out = (float*)d_out;
  (void)in_sizes; (void)n_in; (void)out_size; (void)ws_size;

  char* ws = (char*)d_ws;
  size_t o = 0;
  auto alloc = [&](size_t bytes) -> char* {
    char* p = ws + o;
    o = (o + bytes + 255) & ~(size_t)255;
    return p;
  };
  int* cnt_d = (int*)alloc(NBUCK * 4);   // [0,1024)   zeroed
  int* cnt_s = (int*)alloc(NBUCK * 4);   // [1024,2048) zeroed
  int* ctrs = (int*)alloc(256);          // [2048,2304) zeroed: 0=binA,
                                         // 1..4=gemm layers, 5=gsum
  int* base_d = (int*)alloc((NBUCK + 1) * 4);
  int* cur_d = (int*)alloc(NBUCK * 4);
  int* base_s = (int*)alloc((NBUCK + 1) * 4);
  int* cur_s = (int*)alloc(NBUCK * 4);
  int* bh_d = (int*)alloc((size_t)256 * NBUCK * 4);
  int* bh_s = (int*)alloc((size_t)256 * NBUCK * 4);
  float* norm_src = (float*)alloc(N_NODES * 4);
  float* norm_dst = (float*)alloc(N_NODES * 4);
  int* row_start = (int*)alloc((N_NODES + 1) * 4);
  int* csr_src = (int*)alloc((size_t)N_EDGES * 4);
  int* packed = (int*)alloc((size_t)N_EDGES * 4);
  unsigned short* locs = (unsigned short*)alloc((size_t)N_EDGES * 2);
  float* stats4 = (float*)alloc((size_t)N_LAYERS * SREP * 256 * 4);
  float* gsum = (float*)alloc(N_GRAPHS * 128 * 4);  // adjacent to stats4
  float* sc_sh = (float*)alloc(256 * 4);
  __half* Bsw = (__half*)alloc(5 * 16384 * 2);
  __half* A16 = (__half*)alloc((size_t)N_NODES * 128 * 2);  // residual (fp16)
  unsigned char* P0f8 = (unsigned char*)alloc((size_t)N_NODES * 128);  // fp8
  __half* P1h = (__half*)alloc((size_t)N_NODES * 128 * 2);  // agg (fp16)
  __half* H16 = (__half*)alloc((size_t)N_NODES * 128 * 2);  // hl (fp16)

  // zero bucket counters + done-counters; zero stats replicas + gsum
  hipMemsetAsync(cnt_d, 0, 2304, stream);
  hipMemsetAsync(stats4, 0, (size_t)N_LAYERS * SREP * 256 * 4 + 65536, stream);

  // ---- radix CSR build (+ wswz + scan folded into binA) ----
  binA_k<<<296, 256, 0, stream>>>(src, dst, cnt_d, cnt_s, bh_d, bh_s, base_d,
                                  cur_d, base_s, cur_s, row_start, W_embed,
                                  W_layers, Bsw, ctrs);
  scat_k<<<256, 256, 0, stream>>>(src, dst, cur_d, cur_s, bh_d, bh_s, packed,
                                  locs);
  cdcs_k<<<2 * NBUCK, 256, 0, stream>>>(base_d, packed, row_start, csr_src,
                                        norm_dst, base_s, locs, norm_src);

  // embed: A16 = fp16(h @ W_embed + b) ; P0f8 = fp8(. * norm_src)
  mfma_gemm_f32in<<<(N_NODES + 63) / 64, 256, 0, stream>>>(
      h, Bsw, b_embed, A16, P0f8, norm_src);

  for (int l = 0; l < N_LAYERS; ++l) {
    float* stats = stats4 + (size_t)l * SREP * 256;
    gather16_k<<<(N_NODES * 16 + 255) / 256, 256, 0, stream>>>(
        (const uint2*)P0f8, row_start, csr_src, norm_dst, P1h);
    mfma_gemm_f16<<<(N_NODES + 63) / 64, 256, 0, stream>>>(
        P1h, Bsw + (size_t)(1 + l) * 16384, b_layers + l * DIM, H16, stats,
        gamma + l * DIM, beta + l * DIM, sc_sh, ctrs + 1 + l);
    bnrelu_k<<<(N_NODES * 16 + 255) / 256, 256, 0, stream>>>(
        H16, A16, P0f8, sc_sh, norm_src, (l < N_LAYERS - 1) ? 1 : 0);
  }

  gsum_k<<<(N_NODES + 127) / 128, 128, 0, stream>>>(A16, gid, gsum, out,
                                                    ctrs + 5);
}

// Round 10
// 517.193 us; speedup vs baseline: 1.7531x; 1.0844x over previous
//
#include <hip/hip_runtime.h>
#include <hip/hip_bf16.h>
#include <hip/hip_fp16.h>

// GCN forward. fp16 inter-layer tensors; gather operand fp8 e4m3 (one
// 128B cache line per row); fp32 accum everywhere.
// R3: MFMA GEMM, pre-swizzled W. R7: radix-bucketed CSR build.
// R8: 64-row GEMM tiles; fp16 residual. R10: fp8 gather operand.
// R11: BN stats 64x-replicated. R12: uint-vector gather, persisted
//     histograms, fused norms. R13: coalesced GEMM epilogues (LDS xpose).
// R15: de-fused gather, 16 lanes/node uint2, launch_bounds(256,8).
// R16: index-prefetch pipeline; merged cdcs_k; gout inline binsearch.
// R18-R20: slab-major gather FAILED (4x L2 transactions/edge). Reverted.
// R21: last-block launch fusions FAILED (+56 us): folding gout into
//     gsum's last block serialized 128-block-parallel work into one
//     block; launch gaps measured ~2 us (not worth fusing). Reverted.
// R22: R17 structure + PARALLEL gsum: 16 col-groups x 8 node-lanes per
//     block (float4 reads, coalesced), per-thread graph-run tracking,
//     atomicAdd flush per run. Serial depth 128 -> 16 iterations
//     (gsum was latency-bound at 380 cyc/node: 38-61 us -> ~8).

#define N_NODES 100000
#define N_EDGES 1600000
#define N_GRAPHS 128
#define DIM 128
#define N_LAYERS 4
#define BN_EPS 1e-5f
#define NBUCK 196          // ceil(N_NODES/512)
#define EPB 6250           // edges per block in bin/scatter passes (256 blocks)
#define SREP 64            // stats replicas (atomic-chain 1563 -> ~24)

typedef __attribute__((ext_vector_type(8))) _Float16 half8;
typedef __attribute__((ext_vector_type(4))) float floatx4;
typedef __attribute__((ext_vector_type(2))) float floatx2;

// ---------------- pass A: bucket counts + per-block histograms ----------------
__global__ __launch_bounds__(256) void binA_k(const int* __restrict__ src,
                                              const int* __restrict__ dst,
                                              int* __restrict__ cnt_d,
                                              int* __restrict__ cnt_s,
                                              int* __restrict__ bh_d,
                                              int* __restrict__ bh_s) {
  __shared__ int hd[NBUCK], hs[NBUCK];
  int t = threadIdx.x;
  for (int i = t; i < NBUCK; i += 256) { hd[i] = 0; hs[i] = 0; }
  __syncthreads();
  int e0 = blockIdx.x * EPB;
  for (int e = e0 + t; e < e0 + EPB; e += 256) {
    atomicAdd(&hd[dst[e] >> 9], 1);
    atomicAdd(&hs[src[e] >> 9], 1);
  }
  __syncthreads();
  for (int i = t; i < NBUCK; i += 256) {
    int v = hd[i], v2 = hs[i];
    bh_d[blockIdx.x * NBUCK + i] = v;
    bh_s[blockIdx.x * NBUCK + i] = v2;
    if (v) atomicAdd(&cnt_d[i], v);
    if (v2) atomicAdd(&cnt_s[i], v2);
  }
}

// ---------------- scan of bucket counts -> bases + cursors ----------------
__global__ __launch_bounds__(256) void scan196_k(
    const int* __restrict__ cnt_d, const int* __restrict__ cnt_s,
    int* __restrict__ base_d, int* __restrict__ cur_d,
    int* __restrict__ base_s, int* __restrict__ cur_s,
    int* __restrict__ row_start) {
  __shared__ int sd[256], ss[256];
  int t = threadIdx.x;
  int vd = (t < NBUCK) ? cnt_d[t] : 0;
  int vs = (t < NBUCK) ? cnt_s[t] : 0;
  sd[t] = vd;
  ss[t] = vs;
  __syncthreads();
  for (int off = 1; off < 256; off <<= 1) {
    int ad = (t >= off) ? sd[t - off] : 0;
    int as = (t >= off) ? ss[t - off] : 0;
    __syncthreads();
    sd[t] += ad;
    ss[t] += as;
    __syncthreads();
  }
  if (t < NBUCK) {
    base_d[t] = sd[t] - vd;
    cur_d[t] = sd[t] - vd;
    base_s[t] = ss[t] - vs;
    cur_s[t] = ss[t] - vs;
  }
  if (t == 0) {
    base_d[NBUCK] = N_EDGES;
    base_s[NBUCK] = N_EDGES;
    row_start[N_NODES] = N_EDGES;
  }
}

// ---------------- pass B: scatter edges into bucket regions ----------------
__global__ __launch_bounds__(256) void scat_k(
    const int* __restrict__ src, const int* __restrict__ dst,
    int* __restrict__ cur_d, int* __restrict__ cur_s,
    const int* __restrict__ bh_d, const int* __restrict__ bh_s,
    int* __restrict__ packed, unsigned short* __restrict__ locs) {
  __shared__ int hd[NBUCK], hs[NBUCK];
  int t = threadIdx.x;
  for (int i = t; i < NBUCK; i += 256) {
    hd[i] = bh_d[blockIdx.x * NBUCK + i];
    hs[i] = bh_s[blockIdx.x * NBUCK + i];
  }
  __syncthreads();
  if (t < NBUCK) {  // claim chunks; hd/hs become running cursors
    hd[t] = atomicAdd(&cur_d[t], hd[t]);
    hs[t] = atomicAdd(&cur_s[t], hs[t]);
  }
  __syncthreads();
  int e0 = blockIdx.x * EPB;
  for (int e = e0 + t; e < e0 + EPB; e += 256) {
    int s = src[e], d = dst[e];
    int slot = atomicAdd(&hd[d >> 9], 1);
    packed[slot] = ((d & 511) << 17) | s;
    int slot2 = atomicAdd(&hs[s >> 9], 1);
    locs[slot2] = (unsigned short)(s & 511);
  }
}

// ---------------- pass C (merged): dst CSR fill + norms ----------------
__global__ __launch_bounds__(256) void cdcs_k(
    const int* __restrict__ base_d, const int* __restrict__ packed,
    int* __restrict__ row_start, int* __restrict__ csr_src,
    float* __restrict__ norm_dst, const int* __restrict__ base_s,
    const unsigned short* __restrict__ locs, float* __restrict__ norm_src) {
  __shared__ int sdeg[512], sinc[512], scur[512];
  int t = threadIdx.x;
  if (blockIdx.x >= NBUCK) {  // ---- src-degree histogram -> norm_src ----
    int b = blockIdx.x - NBUCK;
    int nbase = b << 9;
    int e0 = base_s[b], e1 = base_s[b + 1];
    sdeg[t] = 0;
    sdeg[t + 256] = 0;
    __syncthreads();
    for (int e = e0 + t; e < e1; e += 256) atomicAdd(&sdeg[locs[e]], 1);
    __syncthreads();
#pragma unroll
    for (int half = 0; half < 2; ++half) {
      int j = t + half * 256;
      int node = nbase + j;
      if (node < N_NODES) {
        int d = sdeg[j];
        norm_src[node] = rsqrtf((float)(d > 1 ? d : 1));
      }
    }
    return;
  }
  // ---- dst side ----
  int b = blockIdx.x;
  int nbase = b << 9;
  int e0 = base_d[b], e1 = base_d[b + 1];
  sdeg[t] = 0;
  sdeg[t + 256] = 0;
  __syncthreads();
  for (int e = e0 + t; e < e1; e += 256) atomicAdd(&sdeg[packed[e] >> 17], 1);
  __syncthreads();
  sinc[t] = sdeg[t];
  sinc[t + 256] = sdeg[t + 256];
  __syncthreads();
  for (int off = 1; off < 512; off <<= 1) {
    int a0 = (t >= off) ? sinc[t - off] : 0;
    int i1 = t + 256;
    int a1 = (i1 >= off) ? sinc[i1 - off] : 0;
    __syncthreads();
    sinc[t] += a0;
    sinc[i1] += a1;
    __syncthreads();
  }
#pragma unroll
  for (int half = 0; half < 2; ++half) {
    int j = t + half * 256;
    int lofs = e0 + sinc[j] - sdeg[j];
    scur[j] = lofs;
    int node = nbase + j;
    if (node < N_NODES) {
      row_start[node] = lofs;
      int d = sdeg[j];
      norm_dst[node] = rsqrtf((float)(d > 1 ? d : 1));
    }
  }
  __syncthreads();
  for (int e = e0 + t; e < e1; e += 256) {
    int p = packed[e];
    int slot = atomicAdd(&scur[p >> 17], 1);
    csr_src[slot] = p & 0x1FFFF;
  }
}

// ---------------- W pre-swizzle (all 5 matrices, one launch) ----------------
__global__ __launch_bounds__(256) void wswz_k(const float* __restrict__ W_embed,
                                              const float* __restrict__ W_layers,
                                              __half* __restrict__ Bsw) {
  int m = blockIdx.x >> 3, ct = blockIdx.x & 7;  // m: 0=embed, 1..4=layers
  const float* Wm =
      (m == 0) ? W_embed : (W_layers + (size_t)(m - 1) * 16384);
  int ks = threadIdx.x >> 6, lane = threadIdx.x & 63;
  int n = ct * 16 + (lane & 15);
  int k0 = ks * 32 + (lane >> 4) * 8;
  __half* o = Bsw + ((((size_t)m * 8 + ct) * 4 + ks) * 64 + lane) * 8;
#pragma unroll
  for (int j = 0; j < 8; ++j) o[j] = __float2half(Wm[(k0 + j) * 128 + n]);
}

// ---------------- MFMA core: wave w computes 16 rows x 128 cols ----------
// C layout per 16x16 tile: row = quad*4 + reg, col = ct*16 + lrow.
__device__ inline void mfma_core16(const __half* sA,
                                   const __half* __restrict__ Bsw,
                                   floatx4 (&acc)[8], int w, int lane,
                                   int quad, int lrow) {
#pragma unroll
  for (int ct = 0; ct < 8; ++ct) acc[ct] = (floatx4)(0.f);
#pragma unroll
  for (int ks = 0; ks < 4; ++ks) {
    int m = w * 16 + lrow;
    half8 afrag = *(const half8*)(&sA[m * 136 + ks * 32 + quad * 8]);
#pragma unroll
    for (int ct = 0; ct < 8; ++ct) {
      half8 bfrag = *(const half8*)(&Bsw[(((size_t)ct * 4 + ks) * 64 + lane) * 8]);
      acc[ct] = __builtin_amdgcn_mfma_f32_16x16x32_f16(afrag, bfrag, acc[ct],
                                                       0, 0, 0);
    }
  }
}

// ---------------- fp8 accumulate helper (8 cols / lane) ----------------
__device__ inline void accf8x8(float (&a)[8], uint2 v) {
  floatx2 f;
  f = __builtin_amdgcn_cvt_pk_f32_fp8(v.x, false); a[0] += f.x; a[1] += f.y;
  f = __builtin_amdgcn_cvt_pk_f32_fp8(v.x, true);  a[2] += f.x; a[3] += f.y;
  f = __builtin_amdgcn_cvt_pk_f32_fp8(v.y, false); a[4] += f.x; a[5] += f.y;
  f = __builtin_amdgcn_cvt_pk_f32_fp8(v.y, true);  a[6] += f.x; a[7] += f.y;
}

// ---------------- embed GEMM: A16 = fp16(h @ W + b); S8 = fp8(.*ns) ------
// Epilogue: fp32 C staged to LDS in two 32-row rounds -> coalesced stores.
__global__ __launch_bounds__(256) void mfma_gemm_f32in(
    const float* __restrict__ X32, const __half* __restrict__ Bsw,
    const float* __restrict__ bias, __half* __restrict__ A16,
    unsigned char* __restrict__ S8, const float* __restrict__ norm_src) {
  __shared__ __half sA[64 * 136];  // 17.4 KB; reused as fp32 C half-tile
  const int tid = threadIdx.x;
  const int w = tid >> 6, lane = tid & 63;
  const int quad = lane >> 4, lrow = lane & 15;
  const int row_base = blockIdx.x * 64;

  // stage fp32 tile -> fp16 LDS (2048 float4 reads)
#pragma unroll
  for (int i = 0; i < 8; ++i) {
    int g = i * 256 + tid;
    int r = g >> 5, q = g & 31;
    int row = row_base + r;
    float4 v = make_float4(0.f, 0.f, 0.f, 0.f);
    if (row < N_NODES) v = ((const float4*)X32)[(size_t)row * 32 + q];
    union { __half2 h[2]; float f[2]; } u;
    u.h[0] = __floats2half2_rn(v.x, v.y);
    u.h[1] = __floats2half2_rn(v.z, v.w);
    *(float2*)(&sA[r * 136 + q * 4]) = *(float2*)u.f;
  }
  __syncthreads();

  floatx4 acc[8];
  mfma_core16(sA, Bsw, acc, w, lane, quad, lrow);

  float bcol[8];
#pragma unroll
  for (int ct = 0; ct < 8; ++ct) bcol[ct] = bias[ct * 16 + lrow];

  float* sC = (float*)sA;  // [32][132] fp32 (16896 B <= 17408 B)
#pragma unroll
  for (int h = 0; h < 2; ++h) {
    __syncthreads();  // h=0: all mfma LDS reads done; h=1: readback done
    if ((w >> 1) == h) {
      int hw = w & 1;
#pragma unroll
      for (int ct = 0; ct < 8; ++ct)
#pragma unroll
        for (int reg = 0; reg < 4; ++reg)
          sC[(hw * 16 + quad * 4 + reg) * 132 + ct * 16 + lrow] =
              acc[ct][reg] + bcol[ct];
    }
    __syncthreads();
#pragma unroll
    for (int k = 0; k < 4; ++k) {
      int c = k * 256 + tid;       // chunk 0..1023 (16B of fp32 each)
      int hr = c >> 5;             // 0..31
      int col = (c & 31) * 4;
      int row = row_base + h * 32 + hr;
      if (row < N_NODES) {
        float4 y = *(const float4*)&sC[hr * 132 + col];
        union { __half2 hh[2]; float2 f; } u;
        u.hh[0] = __floats2half2_rn(y.x, y.y);
        u.hh[1] = __floats2half2_rn(y.z, y.w);
        *(float2*)(A16 + (size_t)row * 128 + col) = u.f;
        float ns = norm_src[row];
        unsigned pb = 0;
        pb = __builtin_amdgcn_cvt_pk_fp8_f32(y.x * ns, y.y * ns, pb, false);
        pb = __builtin_amdgcn_cvt_pk_fp8_f32(y.z * ns, y.w * ns, pb, true);
        *(unsigned*)(S8 + (size_t)row * 128 + col) = pb;
      }
    }
  }
}

// ---------------- standalone gather: 16 lanes/node, VGPR<=64 ----------------
// Lane owns 8 cols (uint2 = 8B of the 128B row; 16 lanes cover the line).
// Software-pipelined: chunk k+1's csr_src indices issue BEFORE chunk k's
// accumulate. Per-column accumulation order unchanged -> bit-exact.
__global__ __launch_bounds__(256, 8) void gather16_k(
    const uint2* __restrict__ Hs, const int* __restrict__ row_start,
    const int* __restrict__ csr_src, const float* __restrict__ norm_dst,
    __half* __restrict__ out) {
  int node = (blockIdx.x * 256 + threadIdx.x) >> 4;
  int l16 = threadIdx.x & 15;
  int l8 = l16 & 7;
  if (node >= N_NODES) return;
  int s0 = row_start[node], s1 = row_start[node + 1];
  float a[8];
#pragma unroll
  for (int i = 0; i < 8; ++i) a[i] = 0.f;
  int deg = s1 - s0;
  int nfull = deg >> 3;
  int e = s0;
  if (nfull) {
    int idx = csr_src[e + l8];
    for (int k = 0; k < nfull; ++k) {
      uint2 v0 = Hs[(size_t)__shfl(idx, 0, 16) * 16 + l16];
      uint2 v1 = Hs[(size_t)__shfl(idx, 1, 16) * 16 + l16];
      uint2 v2 = Hs[(size_t)__shfl(idx, 2, 16) * 16 + l16];
      uint2 v3 = Hs[(size_t)__shfl(idx, 3, 16) * 16 + l16];
      uint2 v4 = Hs[(size_t)__shfl(idx, 4, 16) * 16 + l16];
      uint2 v5 = Hs[(size_t)__shfl(idx, 5, 16) * 16 + l16];
      uint2 v6 = Hs[(size_t)__shfl(idx, 6, 16) * 16 + l16];
      uint2 v7 = Hs[(size_t)__shfl(idx, 7, 16) * 16 + l16];
      // prefetch next chunk's indices (clamped; value unused on last iter)
      int pe = e + 8 + l8;
      int idx_n = csr_src[pe < N_EDGES ? pe : (N_EDGES - 1)];
      accf8x8(a, v0); accf8x8(a, v1); accf8x8(a, v2); accf8x8(a, v3);
      accf8x8(a, v4); accf8x8(a, v5); accf8x8(a, v6); accf8x8(a, v7);
      idx = idx_n;
      e += 8;
    }
  }
  int cnt = s1 - e;
  if (cnt) {
    int idx = (l8 < cnt) ? csr_src[e + l8] : 0;
    int j = 0;
    for (; j + 4 <= cnt; j += 4) {
      uint2 v0 = Hs[(size_t)__shfl(idx, j, 16) * 16 + l16];
      uint2 v1 = Hs[(size_t)__shfl(idx, j + 1, 16) * 16 + l16];
      uint2 v2 = Hs[(size_t)__shfl(idx, j + 2, 16) * 16 + l16];
      uint2 v3 = Hs[(size_t)__shfl(idx, j + 3, 16) * 16 + l16];
      accf8x8(a, v0); accf8x8(a, v1); accf8x8(a, v2); accf8x8(a, v3);
    }
    for (; j < cnt; ++j) {
      accf8x8(a, Hs[(size_t)__shfl(idx, j, 16) * 16 + l16]);
    }
  }
  float nd = norm_dst[node];
  union { __half2 hh[4]; float4 f; } u;
#pragma unroll
  for (int q = 0; q < 4; ++q)
    u.hh[q] = __floats2half2_rn(a[2 * q] * nd, a[2 * q + 1] * nd);
  *(float4*)(out + (size_t)node * 128 + l16 * 8) = u.f;
}

// ---------------- layer GEMM: hl16 = fp16(agg16 @ W + b) + BN stats -------
__global__ __launch_bounds__(256) void mfma_gemm_f16(
    const __half* __restrict__ X16, const __half* __restrict__ Bsw,
    const float* __restrict__ bias, __half* __restrict__ hl16,
    float* __restrict__ stats) {
  __shared__ __half sA[64 * 136];  // A-tile fp16; reused as fp32 C half-tile
  __shared__ float sred[1024];     // cross-wave stats scratch
  const int tid = threadIdx.x;
  const int w = tid >> 6, lane = tid & 63;
  const int quad = lane >> 4, lrow = lane & 15;
  const int row_base = blockIdx.x * 64;

  // stage fp16 tile (1024 float4 reads)
#pragma unroll
  for (int i = 0; i < 4; ++i) {
    int g = i * 256 + tid;
    int r = g >> 4, p = g & 15;
    int row = row_base + r;
    float4 v = make_float4(0.f, 0.f, 0.f, 0.f);
    if (row < N_NODES) v = ((const float4*)X16)[(size_t)row * 16 + p];
    *(float4*)(&sA[r * 136 + p * 8]) = v;
  }
  __syncthreads();

  floatx4 acc[8];
  mfma_core16(sA, Bsw, acc, w, lane, quad, lrow);

  // ---- BN stats from fp32 registers ----
  float bcol[8], psum[8], pqsum[8];
#pragma unroll
  for (int ct = 0; ct < 8; ++ct) {
    bcol[ct] = bias[ct * 16 + lrow];
    psum[ct] = 0.f;
    pqsum[ct] = 0.f;
#pragma unroll
    for (int reg = 0; reg < 4; ++reg) {
      int row = row_base + w * 16 + quad * 4 + reg;
      if (row < N_NODES) {
        float y = acc[ct][reg] + bcol[ct];
        psum[ct] += y;
        pqsum[ct] += y * y;
      }
    }
  }
#pragma unroll
  for (int ct = 0; ct < 8; ++ct) {
    psum[ct] += __shfl_xor(psum[ct], 16, 64);
    psum[ct] += __shfl_xor(psum[ct], 32, 64);
    pqsum[ct] += __shfl_xor(pqsum[ct], 16, 64);
    pqsum[ct] += __shfl_xor(pqsum[ct], 32, 64);
  }
  if (quad == 0) {
#pragma unroll
    for (int ct = 0; ct < 8; ++ct) {
      sred[w * 128 + ct * 16 + lrow] = psum[ct];
      sred[512 + w * 128 + ct * 16 + lrow] = pqsum[ct];
    }
  }
  __syncthreads();
  if (tid < 128) {
    float s = sred[tid] + sred[128 + tid] + sred[256 + tid] + sred[384 + tid];
    float q = sred[512 + tid] + sred[640 + tid] + sred[768 + tid] +
              sred[896 + tid];
    float* st = stats + (size_t)(blockIdx.x & (SREP - 1)) * 256;
    atomicAdd(&st[tid], s);
    atomicAdd(&st[128 + tid], q);
  }

  // ---- coalesced hl16 store via fp32 LDS transpose ----
  float* sC = (float*)sA;  // [32][132] fp32
#pragma unroll
  for (int h = 0; h < 2; ++h) {
    __syncthreads();  // h=0: mfma reads + stats barrier done; h=1: readback done
    if ((w >> 1) == h) {
      int hw = w & 1;
#pragma unroll
      for (int ct = 0; ct < 8; ++ct)
#pragma unroll
        for (int reg = 0; reg < 4; ++reg)
          sC[(hw * 16 + quad * 4 + reg) * 132 + ct * 16 + lrow] =
              acc[ct][reg] + bcol[ct];
    }
    __syncthreads();
#pragma unroll
    for (int k = 0; k < 4; ++k) {
      int c = k * 256 + tid;
      int hr = c >> 5;
      int col = (c & 31) * 4;
      int row = row_base + h * 32 + hr;
      if (row < N_NODES) {
        float4 y = *(const float4*)&sC[hr * 132 + col];
        union { __half2 hh[2]; float2 f; } u;
        u.hh[0] = __floats2half2_rn(y.x, y.y);
        u.hh[1] = __floats2half2_rn(y.z, y.w);
        *(float2*)(hl16 + (size_t)row * 128 + col) = u.f;
      }
    }
  }
}

// ---------------- BN finalize: collapse SREP replicas -> sc_sh ----------
__global__ __launch_bounds__(128) void bn_fin_k(const float* __restrict__ stats,
                                                const float* __restrict__ gamma,
                                                const float* __restrict__ beta,
                                                float* __restrict__ sc_sh) {
  int c = threadIdx.x;
  float s = 0.f, q = 0.f;
  for (int r = 0; r < SREP; ++r) {
    s += stats[r * 256 + c];
    q += stats[r * 256 + 128 + c];
  }
  const float invn = 1.0f / (float)N_NODES;
  float mean = s * invn;
  float var = q * invn - mean * mean;
  var = fmaxf(var, 0.f);
  float sc = gamma[c] * rsqrtf(var + BN_EPS);
  sc_sh[c] = sc;
  sc_sh[128 + c] = beta[c] - mean * sc;
}

// ---------------- BN apply + ReLU + residual ----------------
__global__ __launch_bounds__(256) void bnrelu_k(
    const __half* __restrict__ hl16, __half* __restrict__ A16,
    unsigned char* __restrict__ S8, const float* __restrict__ sc_sh,
    const float* __restrict__ norm_src, int write_scaled) {
  int idx = blockIdx.x * 256 + threadIdx.x;  // < N_NODES*16
  int node = idx >> 4;
  int c8 = idx & 15;
  float4 hv4 = *(const float4*)(hl16 + (size_t)idx * 8);
  float4 av4 = *(const float4*)(A16 + (size_t)idx * 8);
  const __half2* hp = (const __half2*)&hv4;
  const __half2* ap = (const __half2*)&av4;
  const float4* sv = (const float4*)sc_sh;
  float4 s0 = sv[c8 * 2], s1 = sv[c8 * 2 + 1];
  float4 b0 = sv[32 + c8 * 2], b1 = sv[32 + c8 * 2 + 1];
  float n = write_scaled ? norm_src[node] : 0.f;
  float2 f0 = __half22float2(hp[0]), f1 = __half22float2(hp[1]);
  float2 f2 = __half22float2(hp[2]), f3 = __half22float2(hp[3]);
  float2 a0 = __half22float2(ap[0]), a1 = __half22float2(ap[1]);
  float2 a2 = __half22float2(ap[2]), a3 = __half22float2(ap[3]);
  float v[8];
  v[0] = fmaxf(f0.x * s0.x + b0.x, 0.f) + a0.x;
  v[1] = fmaxf(f0.y * s0.y + b0.y, 0.f) + a0.y;
  v[2] = fmaxf(f1.x * s0.z + b0.z, 0.f) + a1.x;
  v[3] = fmaxf(f1.y * s0.w + b0.w, 0.f) + a1.y;
  v[4] = fmaxf(f2.x * s1.x + b1.x, 0.f) + a2.x;
  v[5] = fmaxf(f2.y * s1.y + b1.y, 0.f) + a2.y;
  v[6] = fmaxf(f3.x * s1.z + b1.z, 0.f) + a3.x;
  v[7] = fmaxf(f3.y * s1.w + b1.w, 0.f) + a3.y;
  union { __half2 h[4]; float4 f; } ua;
#pragma unroll
  for (int q = 0; q < 4; ++q)
    ua.h[q] = __floats2half2_rn(v[2 * q], v[2 * q + 1]);
  *(float4*)(A16 + (size_t)idx * 8) = ua.f;
  if (write_scaled) {
    unsigned lo = 0, hi = 0;
    lo = __builtin_amdgcn_cvt_pk_fp8_f32(v[0] * n, v[1] * n, lo, false);
    lo = __builtin_amdgcn_cvt_pk_fp8_f32(v[2] * n, v[3] * n, lo, true);
    hi = __builtin_amdgcn_cvt_pk_fp8_f32(v[4] * n, v[5] * n, hi, false);
    hi = __builtin_amdgcn_cvt_pk_fp8_f32(v[6] * n, v[7] * n, hi, true);
    ((uint2*)S8)[idx] = make_uint2(lo, hi);
  }
}

// ---------------- readout: parallel gsum ----------------
// 128 threads = 16 col-groups (8 cols, float4) x 8 node-lanes; block
// covers 128 nodes in 16 iterations (was 128 serial). Per-thread
// graph-run tracking; atomicAdd flush per run boundary + at end.
__global__ __launch_bounds__(128) void gsum_k(const __half* __restrict__ A16,
                                              const int* __restrict__ gid,
                                              float* gsum) {
  int t = threadIdx.x;
  int c16 = t & 15;    // col group: cols c16*8 .. +8
  int nsub = t >> 4;   // node lane 0..7
  int n0 = blockIdx.x * 128;
  float a[8];
#pragma unroll
  for (int j = 0; j < 8; ++j) a[j] = 0.f;
  int curg = -1;
  for (int k = 0; k < 16; ++k) {
    int n = n0 + k * 8 + nsub;
    if (n < N_NODES) {
      int g = gid[n];
      if (g != curg) {
        if (curg >= 0) {
#pragma unroll
          for (int j = 0; j < 8; ++j) {
            atomicAdd(&gsum[curg * 128 + c16 * 8 + j], a[j]);
            a[j] = 0.f;
          }
        }
        curg = g;
      }
      float4 v = *(const float4*)(A16 + (size_t)n * 128 + c16 * 8);
      const __half2* hp = (const __half2*)&v;
      float2 f0 = __half22float2(hp[0]), f1 = __half22float2(hp[1]);
      float2 f2 = __half22float2(hp[2]), f3 = __half22float2(hp[3]);
      a[0] += f0.x; a[1] += f0.y; a[2] += f1.x; a[3] += f1.y;
      a[4] += f2.x; a[5] += f2.y; a[6] += f3.x; a[7] += f3.y;
    }
  }
  if (curg >= 0) {
#pragma unroll
    for (int j = 0; j < 8; ++j)
      atomicAdd(&gsum[curg * 128 + c16 * 8 + j], a[j]);
  }
}

// gout with inline graph-bounds binary search.
__global__ __launch_bounds__(128) void gout_k(const float* __restrict__ gsum,
                                              const int* __restrict__ gid,
                                              float* __restrict__ out) {
  __shared__ int bnd[2];
  int g = blockIdx.x, c = threadIdx.x;
  if (c < 2) {
    int target = g + c;
    int lo = 0, hi = N_NODES;
    while (lo < hi) {
      int mid = (lo + hi) >> 1;
      if (gid[mid] < target) lo = mid + 1; else hi = mid;
    }
    bnd[c] = lo;
  }
  __syncthreads();
  float cnt = (float)(bnd[1] - bnd[0]);
  if (cnt < 1.f) cnt = 1.f;
  out[g * 128 + c] = gsum[g * 128 + c] / cnt;
}

// ---------------- launch ----------------
extern "C" void kernel_launch(void* const* d_in, const int* in_sizes, int n_in,
                              void* d_out, int out_size, void* d_ws,
                              size_t ws_size, hipStream_t stream) {
  const float* h = (const float*)d_in[0];
  const int* src = (const int*)d_in[1];
  const int* dst = (const int*)d_in[2];
  const int* gid = (const int*)d_in[3];
  const float* W_embed = (const float*)d_in[4];
  const float* b_embed = (const float*)d_in[5];
  const float* W_layers = (const float*)d_in[6];
  const float* b_layers = (const float*)d_in[7];
  const float* gamma = (const float*)d_in[8];
  const float* beta = (const float*)d_in[9];
  float* out = (float*)d_out;
  (void)in_sizes; (void)n_in; (void)out_size; (void)ws_size;

  char* ws = (char*)d_ws;
  size_t o = 0;
  auto alloc = [&](size_t bytes) -> char* {
    char* p = ws + o;
    o = (o + bytes + 255) & ~(size_t)255;
    return p;
  };
  int* cnt_d = (int*)alloc(NBUCK * 4);  // zeroed (one memset w/ cnt_s)
  int* cnt_s = (int*)alloc(NBUCK * 4);
  int* base_d = (int*)alloc((NBUCK + 1) * 4);
  int* cur_d = (int*)alloc(NBUCK * 4);
  int* base_s = (int*)alloc((NBUCK + 1) * 4);
  int* cur_s = (int*)alloc(NBUCK * 4);
  int* bh_d = (int*)alloc((size_t)256 * NBUCK * 4);
  int* bh_s = (int*)alloc((size_t)256 * NBUCK * 4);
  float* norm_src = (float*)alloc(N_NODES * 4);
  float* norm_dst = (float*)alloc(N_NODES * 4);
  int* row_start = (int*)alloc((N_NODES + 1) * 4);
  int* csr_src = (int*)alloc((size_t)N_EDGES * 4);
  int* packed = (int*)alloc((size_t)N_EDGES * 4);
  unsigned short* locs = (unsigned short*)alloc((size_t)N_EDGES * 2);
  float* stats4 = (float*)alloc((size_t)N_LAYERS * SREP * 256 * 4);
  float* gsum = (float*)alloc(N_GRAPHS * 128 * 4);  // adjacent to stats4
  float* sc_sh = (float*)alloc(256 * 4);
  __half* Bsw = (__half*)alloc(5 * 16384 * 2);
  __half* A16 = (__half*)alloc((size_t)N_NODES * 128 * 2);  // residual (fp16)
  unsigned char* P0f8 = (unsigned char*)alloc((size_t)N_NODES * 128);  // fp8
  __half* P1h = (__half*)alloc((size_t)N_NODES * 128 * 2);  // agg (fp16)
  __half* H16 = (__half*)alloc((size_t)N_NODES * 128 * 2);  // hl (fp16)

  // zero bucket counters; zero all per-layer stats replicas + gsum
  hipMemsetAsync(cnt_d, 0, 2048, stream);
  hipMemsetAsync(stats4, 0, (size_t)N_LAYERS * SREP * 256 * 4 + 65536, stream);

  // ---- radix CSR build ----
  binA_k<<<256, 256, 0, stream>>>(src, dst, cnt_d, cnt_s, bh_d, bh_s);
  scan196_k<<<1, 256, 0, stream>>>(cnt_d, cnt_s, base_d, cur_d, base_s, cur_s,
                                   row_start);
  scat_k<<<256, 256, 0, stream>>>(src, dst, cur_d, cur_s, bh_d, bh_s, packed,
                                  locs);
  cdcs_k<<<2 * NBUCK, 256, 0, stream>>>(base_d, packed, row_start, csr_src,
                                        norm_dst, base_s, locs, norm_src);

  wswz_k<<<40, 256, 0, stream>>>(W_embed, W_layers, Bsw);

  // embed: A16 = fp16(h @ W_embed + b) ; P0f8 = fp8(. * norm_src)
  mfma_gemm_f32in<<<(N_NODES + 63) / 64, 256, 0, stream>>>(
      h, Bsw, b_embed, A16, P0f8, norm_src);

  for (int l = 0; l < N_LAYERS; ++l) {
    float* stats = stats4 + (size_t)l * SREP * 256;
    gather16_k<<<(N_NODES * 16 + 255) / 256, 256, 0, stream>>>(
        (const uint2*)P0f8, row_start, csr_src, norm_dst, P1h);
    mfma_gemm_f16<<<(N_NODES + 63) / 64, 256, 0, stream>>>(
        P1h, Bsw + (size_t)(1 + l) * 16384, b_layers + l * DIM, H16, stats);
    bn_fin_k<<<1, 128, 0, stream>>>(stats, gamma + l * DIM, beta + l * DIM,
                                    sc_sh);
    bnrelu_k<<<(N_NODES * 16 + 255) / 256, 256, 0, stream>>>(
        H16, A16, P0f8, sc_sh, norm_src, (l < N_LAYERS - 1) ? 1 : 0);
  }

  gsum_k<<<(N_NODES + 127) / 128, 128, 0, stream>>>(A16, gid, gsum);
  gout_k<<<N_GRAPHS, 128, 0, stream>>>(gsum, gid, out);
}

// Round 11
// 496.677 us; speedup vs baseline: 1.8255x; 1.0413x over previous
//
#include <hip/hip_runtime.h>
#include <hip/hip_bf16.h>
#include <hip/hip_fp16.h>

// GCN forward. fp16 inter-layer tensors; gather operand fp8 e4m3 (one
// 128B cache line per row); fp32 accum everywhere.
// R3: MFMA GEMM, pre-swizzled W. R7: radix-bucketed CSR build.
// R8: 64-row GEMM tiles; fp16 residual. R10: fp8 gather operand.
// R11: BN stats 64x-replicated. R12: uint-vector gather, persisted
//     histograms, fused norms. R13: coalesced GEMM epilogues (LDS xpose).
// R15: de-fused gather, 16 lanes/node uint2, launch_bounds(256,8).
// R16: index-prefetch pipeline; merged cdcs_k.
// R18-R20: slab-major gather FAILED (4x L2 transactions/edge). Reverted.
// R21: last-block launch fusions FAILED (serialized parallel work;
//     launch gaps ~2 us). Reverted.
// R22: per-thread-run atomic gsum FAILED (900K scalar far-atomics on a
//     64KB region: WRITE_SIZE 0.5->29 MB, still ~50 us). Root cause of
//     BOTH slow variants: per-node branch on just-loaded gid serializes
//     (old, 380cy/node) or per-run scalar atomics contend (new).
// R23: branch-free atomic-free readout: one block per graph (gid sorted
//     -> contiguous range via binary search), 512 thr = 64 half2-cols x
//     8 node-lanes, pure strided load+add (no branches -> loads pipeline),
//     LDS-reduce 8 lanes, write out directly. gout_k + gsum buffer gone.

#define N_NODES 100000
#define N_EDGES 1600000
#define N_GRAPHS 128
#define DIM 128
#define N_LAYERS 4
#define BN_EPS 1e-5f
#define NBUCK 196          // ceil(N_NODES/512)
#define EPB 6250           // edges per block in bin/scatter passes (256 blocks)
#define SREP 64            // stats replicas (atomic-chain 1563 -> ~24)

typedef __attribute__((ext_vector_type(8))) _Float16 half8;
typedef __attribute__((ext_vector_type(4))) float floatx4;
typedef __attribute__((ext_vector_type(2))) float floatx2;

// ---------------- pass A: bucket counts + per-block histograms ----------------
__global__ __launch_bounds__(256) void binA_k(const int* __restrict__ src,
                                              const int* __restrict__ dst,
                                              int* __restrict__ cnt_d,
                                              int* __restrict__ cnt_s,
                                              int* __restrict__ bh_d,
                                              int* __restrict__ bh_s) {
  __shared__ int hd[NBUCK], hs[NBUCK];
  int t = threadIdx.x;
  for (int i = t; i < NBUCK; i += 256) { hd[i] = 0; hs[i] = 0; }
  __syncthreads();
  int e0 = blockIdx.x * EPB;
  for (int e = e0 + t; e < e0 + EPB; e += 256) {
    atomicAdd(&hd[dst[e] >> 9], 1);
    atomicAdd(&hs[src[e] >> 9], 1);
  }
  __syncthreads();
  for (int i = t; i < NBUCK; i += 256) {
    int v = hd[i], v2 = hs[i];
    bh_d[blockIdx.x * NBUCK + i] = v;
    bh_s[blockIdx.x * NBUCK + i] = v2;
    if (v) atomicAdd(&cnt_d[i], v);
    if (v2) atomicAdd(&cnt_s[i], v2);
  }
}

// ---------------- scan of bucket counts -> bases + cursors ----------------
__global__ __launch_bounds__(256) void scan196_k(
    const int* __restrict__ cnt_d, const int* __restrict__ cnt_s,
    int* __restrict__ base_d, int* __restrict__ cur_d,
    int* __restrict__ base_s, int* __restrict__ cur_s,
    int* __restrict__ row_start) {
  __shared__ int sd[256], ss[256];
  int t = threadIdx.x;
  int vd = (t < NBUCK) ? cnt_d[t] : 0;
  int vs = (t < NBUCK) ? cnt_s[t] : 0;
  sd[t] = vd;
  ss[t] = vs;
  __syncthreads();
  for (int off = 1; off < 256; off <<= 1) {
    int ad = (t >= off) ? sd[t - off] : 0;
    int as = (t >= off) ? ss[t - off] : 0;
    __syncthreads();
    sd[t] += ad;
    ss[t] += as;
    __syncthreads();
  }
  if (t < NBUCK) {
    base_d[t] = sd[t] - vd;
    cur_d[t] = sd[t] - vd;
    base_s[t] = ss[t] - vs;
    cur_s[t] = ss[t] - vs;
  }
  if (t == 0) {
    base_d[NBUCK] = N_EDGES;
    base_s[NBUCK] = N_EDGES;
    row_start[N_NODES] = N_EDGES;
  }
}

// ---------------- pass B: scatter edges into bucket regions ----------------
__global__ __launch_bounds__(256) void scat_k(
    const int* __restrict__ src, const int* __restrict__ dst,
    int* __restrict__ cur_d, int* __restrict__ cur_s,
    const int* __restrict__ bh_d, const int* __restrict__ bh_s,
    int* __restrict__ packed, unsigned short* __restrict__ locs) {
  __shared__ int hd[NBUCK], hs[NBUCK];
  int t = threadIdx.x;
  for (int i = t; i < NBUCK; i += 256) {
    hd[i] = bh_d[blockIdx.x * NBUCK + i];
    hs[i] = bh_s[blockIdx.x * NBUCK + i];
  }
  __syncthreads();
  if (t < NBUCK) {  // claim chunks; hd/hs become running cursors
    hd[t] = atomicAdd(&cur_d[t], hd[t]);
    hs[t] = atomicAdd(&cur_s[t], hs[t]);
  }
  __syncthreads();
  int e0 = blockIdx.x * EPB;
  for (int e = e0 + t; e < e0 + EPB; e += 256) {
    int s = src[e], d = dst[e];
    int slot = atomicAdd(&hd[d >> 9], 1);
    packed[slot] = ((d & 511) << 17) | s;
    int slot2 = atomicAdd(&hs[s >> 9], 1);
    locs[slot2] = (unsigned short)(s & 511);
  }
}

// ---------------- pass C (merged): dst CSR fill + norms ----------------
__global__ __launch_bounds__(256) void cdcs_k(
    const int* __restrict__ base_d, const int* __restrict__ packed,
    int* __restrict__ row_start, int* __restrict__ csr_src,
    float* __restrict__ norm_dst, const int* __restrict__ base_s,
    const unsigned short* __restrict__ locs, float* __restrict__ norm_src) {
  __shared__ int sdeg[512], sinc[512], scur[512];
  int t = threadIdx.x;
  if (blockIdx.x >= NBUCK) {  // ---- src-degree histogram -> norm_src ----
    int b = blockIdx.x - NBUCK;
    int nbase = b << 9;
    int e0 = base_s[b], e1 = base_s[b + 1];
    sdeg[t] = 0;
    sdeg[t + 256] = 0;
    __syncthreads();
    for (int e = e0 + t; e < e1; e += 256) atomicAdd(&sdeg[locs[e]], 1);
    __syncthreads();
#pragma unroll
    for (int half = 0; half < 2; ++half) {
      int j = t + half * 256;
      int node = nbase + j;
      if (node < N_NODES) {
        int d = sdeg[j];
        norm_src[node] = rsqrtf((float)(d > 1 ? d : 1));
      }
    }
    return;
  }
  // ---- dst side ----
  int b = blockIdx.x;
  int nbase = b << 9;
  int e0 = base_d[b], e1 = base_d[b + 1];
  sdeg[t] = 0;
  sdeg[t + 256] = 0;
  __syncthreads();
  for (int e = e0 + t; e < e1; e += 256) atomicAdd(&sdeg[packed[e] >> 17], 1);
  __syncthreads();
  sinc[t] = sdeg[t];
  sinc[t + 256] = sdeg[t + 256];
  __syncthreads();
  for (int off = 1; off < 512; off <<= 1) {
    int a0 = (t >= off) ? sinc[t - off] : 0;
    int i1 = t + 256;
    int a1 = (i1 >= off) ? sinc[i1 - off] : 0;
    __syncthreads();
    sinc[t] += a0;
    sinc[i1] += a1;
    __syncthreads();
  }
#pragma unroll
  for (int half = 0; half < 2; ++half) {
    int j = t + half * 256;
    int lofs = e0 + sinc[j] - sdeg[j];
    scur[j] = lofs;
    int node = nbase + j;
    if (node < N_NODES) {
      row_start[node] = lofs;
      int d = sdeg[j];
      norm_dst[node] = rsqrtf((float)(d > 1 ? d : 1));
    }
  }
  __syncthreads();
  for (int e = e0 + t; e < e1; e += 256) {
    int p = packed[e];
    int slot = atomicAdd(&scur[p >> 17], 1);
    csr_src[slot] = p & 0x1FFFF;
  }
}

// ---------------- W pre-swizzle (all 5 matrices, one launch) ----------------
__global__ __launch_bounds__(256) void wswz_k(const float* __restrict__ W_embed,
                                              const float* __restrict__ W_layers,
                                              __half* __restrict__ Bsw) {
  int m = blockIdx.x >> 3, ct = blockIdx.x & 7;  // m: 0=embed, 1..4=layers
  const float* Wm =
      (m == 0) ? W_embed : (W_layers + (size_t)(m - 1) * 16384);
  int ks = threadIdx.x >> 6, lane = threadIdx.x & 63;
  int n = ct * 16 + (lane & 15);
  int k0 = ks * 32 + (lane >> 4) * 8;
  __half* o = Bsw + ((((size_t)m * 8 + ct) * 4 + ks) * 64 + lane) * 8;
#pragma unroll
  for (int j = 0; j < 8; ++j) o[j] = __float2half(Wm[(k0 + j) * 128 + n]);
}

// ---------------- MFMA core: wave w computes 16 rows x 128 cols ----------
// C layout per 16x16 tile: row = quad*4 + reg, col = ct*16 + lrow.
__device__ inline void mfma_core16(const __half* sA,
                                   const __half* __restrict__ Bsw,
                                   floatx4 (&acc)[8], int w, int lane,
                                   int quad, int lrow) {
#pragma unroll
  for (int ct = 0; ct < 8; ++ct) acc[ct] = (floatx4)(0.f);
#pragma unroll
  for (int ks = 0; ks < 4; ++ks) {
    int m = w * 16 + lrow;
    half8 afrag = *(const half8*)(&sA[m * 136 + ks * 32 + quad * 8]);
#pragma unroll
    for (int ct = 0; ct < 8; ++ct) {
      half8 bfrag = *(const half8*)(&Bsw[(((size_t)ct * 4 + ks) * 64 + lane) * 8]);
      acc[ct] = __builtin_amdgcn_mfma_f32_16x16x32_f16(afrag, bfrag, acc[ct],
                                                       0, 0, 0);
    }
  }
}

// ---------------- fp8 accumulate helper (8 cols / lane) ----------------
__device__ inline void accf8x8(float (&a)[8], uint2 v) {
  floatx2 f;
  f = __builtin_amdgcn_cvt_pk_f32_fp8(v.x, false); a[0] += f.x; a[1] += f.y;
  f = __builtin_amdgcn_cvt_pk_f32_fp8(v.x, true);  a[2] += f.x; a[3] += f.y;
  f = __builtin_amdgcn_cvt_pk_f32_fp8(v.y, false); a[4] += f.x; a[5] += f.y;
  f = __builtin_amdgcn_cvt_pk_f32_fp8(v.y, true);  a[6] += f.x; a[7] += f.y;
}

// ---------------- embed GEMM: A16 = fp16(h @ W + b); S8 = fp8(.*ns) ------
// Epilogue: fp32 C staged to LDS in two 32-row rounds -> coalesced stores.
__global__ __launch_bounds__(256) void mfma_gemm_f32in(
    const float* __restrict__ X32, const __half* __restrict__ Bsw,
    const float* __restrict__ bias, __half* __restrict__ A16,
    unsigned char* __restrict__ S8, const float* __restrict__ norm_src) {
  __shared__ __half sA[64 * 136];  // 17.4 KB; reused as fp32 C half-tile
  const int tid = threadIdx.x;
  const int w = tid >> 6, lane = tid & 63;
  const int quad = lane >> 4, lrow = lane & 15;
  const int row_base = blockIdx.x * 64;

  // stage fp32 tile -> fp16 LDS (2048 float4 reads)
#pragma unroll
  for (int i = 0; i < 8; ++i) {
    int g = i * 256 + tid;
    int r = g >> 5, q = g & 31;
    int row = row_base + r;
    float4 v = make_float4(0.f, 0.f, 0.f, 0.f);
    if (row < N_NODES) v = ((const float4*)X32)[(size_t)row * 32 + q];
    union { __half2 h[2]; float f[2]; } u;
    u.h[0] = __floats2half2_rn(v.x, v.y);
    u.h[1] = __floats2half2_rn(v.z, v.w);
    *(float2*)(&sA[r * 136 + q * 4]) = *(float2*)u.f;
  }
  __syncthreads();

  floatx4 acc[8];
  mfma_core16(sA, Bsw, acc, w, lane, quad, lrow);

  float bcol[8];
#pragma unroll
  for (int ct = 0; ct < 8; ++ct) bcol[ct] = bias[ct * 16 + lrow];

  float* sC = (float*)sA;  // [32][132] fp32 (16896 B <= 17408 B)
#pragma unroll
  for (int h = 0; h < 2; ++h) {
    __syncthreads();  // h=0: all mfma LDS reads done; h=1: readback done
    if ((w >> 1) == h) {
      int hw = w & 1;
#pragma unroll
      for (int ct = 0; ct < 8; ++ct)
#pragma unroll
        for (int reg = 0; reg < 4; ++reg)
          sC[(hw * 16 + quad * 4 + reg) * 132 + ct * 16 + lrow] =
              acc[ct][reg] + bcol[ct];
    }
    __syncthreads();
#pragma unroll
    for (int k = 0; k < 4; ++k) {
      int c = k * 256 + tid;       // chunk 0..1023 (16B of fp32 each)
      int hr = c >> 5;             // 0..31
      int col = (c & 31) * 4;
      int row = row_base + h * 32 + hr;
      if (row < N_NODES) {
        float4 y = *(const float4*)&sC[hr * 132 + col];
        union { __half2 hh[2]; float2 f; } u;
        u.hh[0] = __floats2half2_rn(y.x, y.y);
        u.hh[1] = __floats2half2_rn(y.z, y.w);
        *(float2*)(A16 + (size_t)row * 128 + col) = u.f;
        float ns = norm_src[row];
        unsigned pb = 0;
        pb = __builtin_amdgcn_cvt_pk_fp8_f32(y.x * ns, y.y * ns, pb, false);
        pb = __builtin_amdgcn_cvt_pk_fp8_f32(y.z * ns, y.w * ns, pb, true);
        *(unsigned*)(S8 + (size_t)row * 128 + col) = pb;
      }
    }
  }
}

// ---------------- standalone gather: 16 lanes/node, VGPR<=64 ----------------
// Lane owns 8 cols (uint2 = 8B of the 128B row; 16 lanes cover the line).
// Software-pipelined: chunk k+1's csr_src indices issue BEFORE chunk k's
// accumulate. Per-column accumulation order unchanged -> bit-exact.
__global__ __launch_bounds__(256, 8) void gather16_k(
    const uint2* __restrict__ Hs, const int* __restrict__ row_start,
    const int* __restrict__ csr_src, const float* __restrict__ norm_dst,
    __half* __restrict__ out) {
  int node = (blockIdx.x * 256 + threadIdx.x) >> 4;
  int l16 = threadIdx.x & 15;
  int l8 = l16 & 7;
  if (node >= N_NODES) return;
  int s0 = row_start[node], s1 = row_start[node + 1];
  float a[8];
#pragma unroll
  for (int i = 0; i < 8; ++i) a[i] = 0.f;
  int deg = s1 - s0;
  int nfull = deg >> 3;
  int e = s0;
  if (nfull) {
    int idx = csr_src[e + l8];
    for (int k = 0; k < nfull; ++k) {
      uint2 v0 = Hs[(size_t)__shfl(idx, 0, 16) * 16 + l16];
      uint2 v1 = Hs[(size_t)__shfl(idx, 1, 16) * 16 + l16];
      uint2 v2 = Hs[(size_t)__shfl(idx, 2, 16) * 16 + l16];
      uint2 v3 = Hs[(size_t)__shfl(idx, 3, 16) * 16 + l16];
      uint2 v4 = Hs[(size_t)__shfl(idx, 4, 16) * 16 + l16];
      uint2 v5 = Hs[(size_t)__shfl(idx, 5, 16) * 16 + l16];
      uint2 v6 = Hs[(size_t)__shfl(idx, 6, 16) * 16 + l16];
      uint2 v7 = Hs[(size_t)__shfl(idx, 7, 16) * 16 + l16];
      // prefetch next chunk's indices (clamped; value unused on last iter)
      int pe = e + 8 + l8;
      int idx_n = csr_src[pe < N_EDGES ? pe : (N_EDGES - 1)];
      accf8x8(a, v0); accf8x8(a, v1); accf8x8(a, v2); accf8x8(a, v3);
      accf8x8(a, v4); accf8x8(a, v5); accf8x8(a, v6); accf8x8(a, v7);
      idx = idx_n;
      e += 8;
    }
  }
  int cnt = s1 - e;
  if (cnt) {
    int idx = (l8 < cnt) ? csr_src[e + l8] : 0;
    int j = 0;
    for (; j + 4 <= cnt; j += 4) {
      uint2 v0 = Hs[(size_t)__shfl(idx, j, 16) * 16 + l16];
      uint2 v1 = Hs[(size_t)__shfl(idx, j + 1, 16) * 16 + l16];
      uint2 v2 = Hs[(size_t)__shfl(idx, j + 2, 16) * 16 + l16];
      uint2 v3 = Hs[(size_t)__shfl(idx, j + 3, 16) * 16 + l16];
      accf8x8(a, v0); accf8x8(a, v1); accf8x8(a, v2); accf8x8(a, v3);
    }
    for (; j < cnt; ++j) {
      accf8x8(a, Hs[(size_t)__shfl(idx, j, 16) * 16 + l16]);
    }
  }
  float nd = norm_dst[node];
  union { __half2 hh[4]; float4 f; } u;
#pragma unroll
  for (int q = 0; q < 4; ++q)
    u.hh[q] = __floats2half2_rn(a[2 * q] * nd, a[2 * q + 1] * nd);
  *(float4*)(out + (size_t)node * 128 + l16 * 8) = u.f;
}

// ---------------- layer GEMM: hl16 = fp16(agg16 @ W + b) + BN stats -------
__global__ __launch_bounds__(256) void mfma_gemm_f16(
    const __half* __restrict__ X16, const __half* __restrict__ Bsw,
    const float* __restrict__ bias, __half* __restrict__ hl16,
    float* __restrict__ stats) {
  __shared__ __half sA[64 * 136];  // A-tile fp16; reused as fp32 C half-tile
  __shared__ float sred[1024];     // cross-wave stats scratch
  const int tid = threadIdx.x;
  const int w = tid >> 6, lane = tid & 63;
  const int quad = lane >> 4, lrow = lane & 15;
  const int row_base = blockIdx.x * 64;

  // stage fp16 tile (1024 float4 reads)
#pragma unroll
  for (int i = 0; i < 4; ++i) {
    int g = i * 256 + tid;
    int r = g >> 4, p = g & 15;
    int row = row_base + r;
    float4 v = make_float4(0.f, 0.f, 0.f, 0.f);
    if (row < N_NODES) v = ((const float4*)X16)[(size_t)row * 16 + p];
    *(float4*)(&sA[r * 136 + p * 8]) = v;
  }
  __syncthreads();

  floatx4 acc[8];
  mfma_core16(sA, Bsw, acc, w, lane, quad, lrow);

  // ---- BN stats from fp32 registers ----
  float bcol[8], psum[8], pqsum[8];
#pragma unroll
  for (int ct = 0; ct < 8; ++ct) {
    bcol[ct] = bias[ct * 16 + lrow];
    psum[ct] = 0.f;
    pqsum[ct] = 0.f;
#pragma unroll
    for (int reg = 0; reg < 4; ++reg) {
      int row = row_base + w * 16 + quad * 4 + reg;
      if (row < N_NODES) {
        float y = acc[ct][reg] + bcol[ct];
        psum[ct] += y;
        pqsum[ct] += y * y;
      }
    }
  }
#pragma unroll
  for (int ct = 0; ct < 8; ++ct) {
    psum[ct] += __shfl_xor(psum[ct], 16, 64);
    psum[ct] += __shfl_xor(psum[ct], 32, 64);
    pqsum[ct] += __shfl_xor(pqsum[ct], 16, 64);
    pqsum[ct] += __shfl_xor(pqsum[ct], 32, 64);
  }
  if (quad == 0) {
#pragma unroll
    for (int ct = 0; ct < 8; ++ct) {
      sred[w * 128 + ct * 16 + lrow] = psum[ct];
      sred[512 + w * 128 + ct * 16 + lrow] = pqsum[ct];
    }
  }
  __syncthreads();
  if (tid < 128) {
    float s = sred[tid] + sred[128 + tid] + sred[256 + tid] + sred[384 + tid];
    float q = sred[512 + tid] + sred[640 + tid] + sred[768 + tid] +
              sred[896 + tid];
    float* st = stats + (size_t)(blockIdx.x & (SREP - 1)) * 256;
    atomicAdd(&st[tid], s);
    atomicAdd(&st[128 + tid], q);
  }

  // ---- coalesced hl16 store via fp32 LDS transpose ----
  float* sC = (float*)sA;  // [32][132] fp32
#pragma unroll
  for (int h = 0; h < 2; ++h) {
    __syncthreads();  // h=0: mfma reads + stats barrier done; h=1: readback done
    if ((w >> 1) == h) {
      int hw = w & 1;
#pragma unroll
      for (int ct = 0; ct < 8; ++ct)
#pragma unroll
        for (int reg = 0; reg < 4; ++reg)
          sC[(hw * 16 + quad * 4 + reg) * 132 + ct * 16 + lrow] =
              acc[ct][reg] + bcol[ct];
    }
    __syncthreads();
#pragma unroll
    for (int k = 0; k < 4; ++k) {
      int c = k * 256 + tid;
      int hr = c >> 5;
      int col = (c & 31) * 4;
      int row = row_base + h * 32 + hr;
      if (row < N_NODES) {
        float4 y = *(const float4*)&sC[hr * 132 + col];
        union { __half2 hh[2]; float2 f; } u;
        u.hh[0] = __floats2half2_rn(y.x, y.y);
        u.hh[1] = __floats2half2_rn(y.z, y.w);
        *(float2*)(hl16 + (size_t)row * 128 + col) = u.f;
      }
    }
  }
}

// ---------------- BN finalize: collapse SREP replicas -> sc_sh ----------
__global__ __launch_bounds__(128) void bn_fin_k(const float* __restrict__ stats,
                                                const float* __restrict__ gamma,
                                                const float* __restrict__ beta,
                                                float* __restrict__ sc_sh) {
  int c = threadIdx.x;
  float s = 0.f, q = 0.f;
  for (int r = 0; r < SREP; ++r) {
    s += stats[r * 256 + c];
    q += stats[r * 256 + 128 + c];
  }
  const float invn = 1.0f / (float)N_NODES;
  float mean = s * invn;
  float var = q * invn - mean * mean;
  var = fmaxf(var, 0.f);
  float sc = gamma[c] * rsqrtf(var + BN_EPS);
  sc_sh[c] = sc;
  sc_sh[128 + c] = beta[c] - mean * sc;
}

// ---------------- BN apply + ReLU + residual ----------------
__global__ __launch_bounds__(256) void bnrelu_k(
    const __half* __restrict__ hl16, __half* __restrict__ A16,
    unsigned char* __restrict__ S8, const float* __restrict__ sc_sh,
    const float* __restrict__ norm_src, int write_scaled) {
  int idx = blockIdx.x * 256 + threadIdx.x;  // < N_NODES*16
  int node = idx >> 4;
  int c8 = idx & 15;
  float4 hv4 = *(const float4*)(hl16 + (size_t)idx * 8);
  float4 av4 = *(const float4*)(A16 + (size_t)idx * 8);
  const __half2* hp = (const __half2*)&hv4;
  const __half2* ap = (const __half2*)&av4;
  const float4* sv = (const float4*)sc_sh;
  float4 s0 = sv[c8 * 2], s1 = sv[c8 * 2 + 1];
  float4 b0 = sv[32 + c8 * 2], b1 = sv[32 + c8 * 2 + 1];
  float n = write_scaled ? norm_src[node] : 0.f;
  float2 f0 = __half22float2(hp[0]), f1 = __half22float2(hp[1]);
  float2 f2 = __half22float2(hp[2]), f3 = __half22float2(hp[3]);
  float2 a0 = __half22float2(ap[0]), a1 = __half22float2(ap[1]);
  float2 a2 = __half22float2(ap[2]), a3 = __half22float2(ap[3]);
  float v[8];
  v[0] = fmaxf(f0.x * s0.x + b0.x, 0.f) + a0.x;
  v[1] = fmaxf(f0.y * s0.y + b0.y, 0.f) + a0.y;
  v[2] = fmaxf(f1.x * s0.z + b0.z, 0.f) + a1.x;
  v[3] = fmaxf(f1.y * s0.w + b0.w, 0.f) + a1.y;
  v[4] = fmaxf(f2.x * s1.x + b1.x, 0.f) + a2.x;
  v[5] = fmaxf(f2.y * s1.y + b1.y, 0.f) + a2.y;
  v[6] = fmaxf(f3.x * s1.z + b1.z, 0.f) + a3.x;
  v[7] = fmaxf(f3.y * s1.w + b1.w, 0.f) + a3.y;
  union { __half2 h[4]; float4 f; } ua;
#pragma unroll
  for (int q = 0; q < 4; ++q)
    ua.h[q] = __floats2half2_rn(v[2 * q], v[2 * q + 1]);
  *(float4*)(A16 + (size_t)idx * 8) = ua.f;
  if (write_scaled) {
    unsigned lo = 0, hi = 0;
    lo = __builtin_amdgcn_cvt_pk_fp8_f32(v[0] * n, v[1] * n, lo, false);
    lo = __builtin_amdgcn_cvt_pk_fp8_f32(v[2] * n, v[3] * n, lo, true);
    hi = __builtin_amdgcn_cvt_pk_fp8_f32(v[4] * n, v[5] * n, hi, false);
    hi = __builtin_amdgcn_cvt_pk_fp8_f32(v[6] * n, v[7] * n, hi, true);
    ((uint2*)S8)[idx] = make_uint2(lo, hi);
  }
}

// ---------------- readout: one block per graph, branch-free -------------
// gid sorted -> graph g occupies contiguous [lo,hi). 512 threads =
// 64 half2-col-groups x 8 node-lanes; pure strided load+add (loads
// pipeline freely, no data-dependent branches, no atomics). LDS-reduce
// the 8 node-lanes, divide by count, write out directly.
__global__ __launch_bounds__(512) void gsum2_k(const __half* __restrict__ A16,
                                               const int* __restrict__ gid,
                                               float* __restrict__ out) {
  __shared__ int bnd[2];
  __shared__ float sred[8][128];
  int g = blockIdx.x;
  int t = threadIdx.x;
  int c2 = t & 63;   // half2 column group (cols 2*c2, 2*c2+1)
  int nl = t >> 6;   // node lane 0..7
  if (t < 2) {
    int target = g + t;
    int lo = 0, hi = N_NODES;
    while (lo < hi) {
      int mid = (lo + hi) >> 1;
      if (gid[mid] < target) lo = mid + 1; else hi = mid;
    }
    bnd[t] = lo;
  }
  __syncthreads();
  int lo = bnd[0], hi = bnd[1];
  float ax = 0.f, ay = 0.f;
  for (int n = lo + nl; n < hi; n += 8) {
    __half2 v = *(const __half2*)(A16 + (size_t)n * 128 + c2 * 2);
    float2 f = __half22float2(v);
    ax += f.x;
    ay += f.y;
  }
  sred[nl][c2 * 2] = ax;
  sred[nl][c2 * 2 + 1] = ay;
  __syncthreads();
  if (t < 128) {
    float s = 0.f;
#pragma unroll
    for (int r = 0; r < 8; ++r) s += sred[r][t];
    float cnt = (float)(hi - lo);
    if (cnt < 1.f) cnt = 1.f;
    out[g * 128 + t] = s / cnt;
  }
}

// ---------------- launch ----------------
extern "C" void kernel_launch(void* const* d_in, const int* in_sizes, int n_in,
                              void* d_out, int out_size, void* d_ws,
                              size_t ws_size, hipStream_t stream) {
  const float* h = (const float*)d_in[0];
  const int* src = (const int*)d_in[1];
  const int* dst = (const int*)d_in[2];
  const int* gid = (const int*)d_in[3];
  const float* W_embed = (const float*)d_in[4];
  const float* b_embed = (const float*)d_in[5];
  const float* W_layers = (const float*)d_in[6];
  const float* b_layers = (const float*)d_in[7];
  const float* gamma = (const float*)d_in[8];
  const float* beta = (const float*)d_in[9];
  float* out = (float*)d_out;
  (void)in_sizes; (void)n_in; (void)out_size; (void)ws_size;

  char* ws = (char*)d_ws;
  size_t o = 0;
  auto alloc = [&](size_t bytes) -> char* {
    char* p = ws + o;
    o = (o + bytes + 255) & ~(size_t)255;
    return p;
  };
  int* cnt_d = (int*)alloc(NBUCK * 4);  // zeroed (one memset w/ cnt_s)
  int* cnt_s = (int*)alloc(NBUCK * 4);
  int* base_d = (int*)alloc((NBUCK + 1) * 4);
  int* cur_d = (int*)alloc(NBUCK * 4);
  int* base_s = (int*)alloc((NBUCK + 1) * 4);
  int* cur_s = (int*)alloc(NBUCK * 4);
  int* bh_d = (int*)alloc((size_t)256 * NBUCK * 4);
  int* bh_s = (int*)alloc((size_t)256 * NBUCK * 4);
  float* norm_src = (float*)alloc(N_NODES * 4);
  float* norm_dst = (float*)alloc(N_NODES * 4);
  int* row_start = (int*)alloc((N_NODES + 1) * 4);
  int* csr_src = (int*)alloc((size_t)N_EDGES * 4);
  int* packed = (int*)alloc((size_t)N_EDGES * 4);
  unsigned short* locs = (unsigned short*)alloc((size_t)N_EDGES * 2);
  float* stats4 = (float*)alloc((size_t)N_LAYERS * SREP * 256 * 4);
  float* sc_sh = (float*)alloc(256 * 4);
  __half* Bsw = (__half*)alloc(5 * 16384 * 2);
  __half* A16 = (__half*)alloc((size_t)N_NODES * 128 * 2);  // residual (fp16)
  unsigned char* P0f8 = (unsigned char*)alloc((size_t)N_NODES * 128);  // fp8
  __half* P1h = (__half*)alloc((size_t)N_NODES * 128 * 2);  // agg (fp16)
  __half* H16 = (__half*)alloc((size_t)N_NODES * 128 * 2);  // hl (fp16)

  // zero bucket counters; zero all per-layer stats replicas
  hipMemsetAsync(cnt_d, 0, 2048, stream);
  hipMemsetAsync(stats4, 0, (size_t)N_LAYERS * SREP * 256 * 4, stream);

  // ---- radix CSR build ----
  binA_k<<<256, 256, 0, stream>>>(src, dst, cnt_d, cnt_s, bh_d, bh_s);
  scan196_k<<<1, 256, 0, stream>>>(cnt_d, cnt_s, base_d, cur_d, base_s, cur_s,
                                   row_start);
  scat_k<<<256, 256, 0, stream>>>(src, dst, cur_d, cur_s, bh_d, bh_s, packed,
                                  locs);
  cdcs_k<<<2 * NBUCK, 256, 0, stream>>>(base_d, packed, row_start, csr_src,
                                        norm_dst, base_s, locs, norm_src);

  wswz_k<<<40, 256, 0, stream>>>(W_embed, W_layers, Bsw);

  // embed: A16 = fp16(h @ W_embed + b) ; P0f8 = fp8(. * norm_src)
  mfma_gemm_f32in<<<(N_NODES + 63) / 64, 256, 0, stream>>>(
      h, Bsw, b_embed, A16, P0f8, norm_src);

  for (int l = 0; l < N_LAYERS; ++l) {
    float* stats = stats4 + (size_t)l * SREP * 256;
    gather16_k<<<(N_NODES * 16 + 255) / 256, 256, 0, stream>>>(
        (const uint2*)P0f8, row_start, csr_src, norm_dst, P1h);
    mfma_gemm_f16<<<(N_NODES + 63) / 64, 256, 0, stream>>>(
        P1h, Bsw + (size_t)(1 + l) * 16384, b_layers + l * DIM, H16, stats);
    bn_fin_k<<<1, 128, 0, stream>>>(stats, gamma + l * DIM, beta + l * DIM,
                                    sc_sh);
    bnrelu_k<<<(N_NODES * 16 + 255) / 256, 256, 0, stream>>>(
        H16, A16, P0f8, sc_sh, norm_src, (l < N_LAYERS - 1) ? 1 : 0);
  }

  gsum2_k<<<N_GRAPHS, 512, 0, stream>>>(A16, gid, out);
}